// Round 1
// baseline (1626.763 us; speedup 1.0000x reference)
//
#include <hip/hip_runtime.h>
#include <math.h>

// Problem constants (MultiHeadAttnBlock): B=8, C=512, T=2048, G=32, HEADS=8, CH=64
#define NB 8
#define NC 512
#define NT 2048
#define NG 32

// ---------------------------------------------------------------------------
// Kernel 1: GroupNorm. One block per (b, g). Group = 16 channels x 2048 t,
// contiguous 32768 floats. Two passes (stats, then normalize), float4.
// ---------------------------------------------------------------------------
__global__ __launch_bounds__(256) void gn_kernel(
    const float* __restrict__ x, const float* __restrict__ gw,
    const float* __restrict__ gb, float* __restrict__ h)
{
    __shared__ float red[16];
    const int tid = threadIdx.x;
    const int grp = blockIdx.x;          // b*32 + gi
    const int b = grp >> 5, gi = grp & 31;
    const size_t off = ((size_t)b * NC + gi * 16) * NT;
    const float4* xp = (const float4*)(x + off);
    float4* hp = (float4*)(h + off);

    float s = 0.f, ss = 0.f;
    for (int i = tid; i < 8192; i += 256) {
        float4 v = xp[i];
        s  += v.x + v.y + v.z + v.w;
        ss += v.x*v.x + v.y*v.y + v.z*v.z + v.w*v.w;
    }
    #pragma unroll
    for (int o = 32; o > 0; o >>= 1) {
        s  += __shfl_down(s,  o, 64);
        ss += __shfl_down(ss, o, 64);
    }
    const int lane = tid & 63, wid = tid >> 6;
    if (lane == 0) { red[wid] = s; red[8 + wid] = ss; }
    __syncthreads();
    if (tid == 0) {
        red[0] = red[0] + red[1] + red[2] + red[3];
        red[8] = red[8] + red[9] + red[10] + red[11];
    }
    __syncthreads();
    const float inv  = 1.f / 32768.f;
    const float mean = red[0] * inv;
    const float var  = red[8] * inv - mean * mean;
    const float rstd = rsqrtf(var + 1e-5f);

    for (int i = tid; i < 8192; i += 256) {
        const int c = gi * 16 + (i >> 9);   // 512 float4 per channel row
        const float wc = gw[c] * rstd;
        const float bc = gb[c] - mean * wc;
        float4 v = xp[i];
        v.x = v.x * wc + bc; v.y = v.y * wc + bc;
        v.z = v.z * wc + bc; v.w = v.w * wc + bc;
        hp[i] = v;
    }
}

// ---------------------------------------------------------------------------
// Kernel 2: batched fp32 GEMM  C[bz] = A @ B[bz] + bias (+ resid[bz])
// A: [M,K] shared across batch. B: [batch][K][N]. 64x64 tile, BK=16,
// 256 threads, 4x4 microtile per thread. LDS stride 68 (pad 4, float4-aligned).
// ---------------------------------------------------------------------------
__global__ __launch_bounds__(256) void gemm_kernel(
    const float* __restrict__ A,     // [M,K]
    const float* __restrict__ Bm,    // [batch][K][N]
    const float* __restrict__ bias,  // [M]
    const float* __restrict__ resid, // [batch][M][N] or nullptr
    float* __restrict__ Cm,          // [batch][M][N]
    int M, int N, int K)
{
    __shared__ __align__(16) float As[16][68];
    __shared__ __align__(16) float Bs[16][68];
    const int tid = threadIdx.x;
    const int tx = tid & 15, ty = tid >> 4;
    const int n0 = blockIdx.x * 64;
    const int m0 = blockIdx.y * 64;
    const int bz = blockIdx.z;
    const float* Bb = Bm + (size_t)bz * K * N;

    float acc[4][4] = {};
    const int am = tid >> 2;          // 0..63 (row within A tile)
    const int ak = (tid & 3) * 4;     // 0,4,8,12
    const int bk = tid >> 4;          // 0..15
    const int bn = (tid & 15) * 4;    // 0..60

    for (int k0 = 0; k0 < K; k0 += 16) {
        float4 av = *(const float4*)(A  + (size_t)(m0 + am) * K + k0 + ak);
        float4 bv = *(const float4*)(Bb + (size_t)(k0 + bk) * N + n0 + bn);
        As[ak + 0][am] = av.x; As[ak + 1][am] = av.y;
        As[ak + 2][am] = av.z; As[ak + 3][am] = av.w;
        *(float4*)&Bs[bk][bn] = bv;
        __syncthreads();
        #pragma unroll
        for (int kk = 0; kk < 16; ++kk) {
            float a4[4], b4[4];
            *(float4*)a4 = *(const float4*)&As[kk][ty * 4];
            *(float4*)b4 = *(const float4*)&Bs[kk][tx * 4];
            #pragma unroll
            for (int i = 0; i < 4; ++i)
                #pragma unroll
                for (int j = 0; j < 4; ++j)
                    acc[i][j] += a4[i] * b4[j];
        }
        __syncthreads();
    }

    for (int i = 0; i < 4; ++i) {
        const int m = m0 + ty * 4 + i;
        const float bv = bias[m];
        const size_t idx = (size_t)bz * M * N + (size_t)m * N + n0 + tx * 4;
        float4 o;
        o.x = acc[i][0] + bv; o.y = acc[i][1] + bv;
        o.z = acc[i][2] + bv; o.w = acc[i][3] + bv;
        if (resid) {
            float4 r = *(const float4*)(resid + idx);
            o.x += r.x; o.y += r.y; o.z += r.z; o.w += r.w;
        }
        *(float4*)(Cm + idx) = o;
    }
}

// ---------------------------------------------------------------------------
// Kernel 3: flash-style attention, fp32.
// Block = (t-tile of 64) x (one of 64 head-batches). 256 threads.
// qkv layout: [b][3C][T]; q/k/v head slice = 64 ch x 2048 t (ch stride T).
// S-phase: thread (tx,ty) computes S[tt=4ty+i][ss=4tx+j] (GEMM over c via LDS).
// Online softmax: row tt lives in a contiguous 16-lane group -> shfl_xor.
// PV-phase: thread (tx,ty) owns O[c=4ty+i][tt=4tx+j]; P transposed via LDS.
// ---------------------------------------------------------------------------
__global__ __launch_bounds__(256) void attn_kernel(
    const float* __restrict__ qkv, float* __restrict__ out)
{
    __shared__ __align__(16) float q_s[64 * 68];   // [c][tt]
    __shared__ __align__(16) float k_s[64 * 68];   // [c][ss]
    __shared__ __align__(16) float vt_s[64 * 68];  // [ss][c]
    __shared__ __align__(16) float p_s[64 * 68];   // [ss][tt]
    __shared__ float alpha_s[64];
    __shared__ float l_s[64];

    const int tid = threadIdx.x;
    const int tx = tid & 15, ty = tid >> 4;
    const int t0 = blockIdx.x * 64;
    const int bh = blockIdx.y;           // 0..63
    const int b = bh >> 3, hd = bh & 7;
    const size_t base = ((size_t)b * (3 * NC) + hd * 64) * NT;
    const float* qg = qkv + base;
    const float* kg = qkv + base + (size_t)NC * NT;
    const float* vg = qkv + base + (size_t)(2 * NC) * NT;
    const float scale = 0.35355339059327373f;   // 64^-0.25

    // stage Q tile (scaled): q_s[c][tt]
    {
        const int cb = tid >> 4;            // 0..15
        const int s4 = (tid & 15) * 4;
        #pragma unroll
        for (int r = 0; r < 4; ++r) {
            const int c = cb + r * 16;
            float4 v = *(const float4*)(qg + (size_t)c * NT + t0 + s4);
            v.x *= scale; v.y *= scale; v.z *= scale; v.w *= scale;
            *(float4*)&q_s[c * 68 + s4] = v;
        }
    }

    float O[4][4] = {};
    float m_run[4], l_run[4];
    #pragma unroll
    for (int i = 0; i < 4; ++i) { m_run[i] = -1e30f; l_run[i] = 0.f; }

    for (int s0 = 0; s0 < NT; s0 += 64) {
        __syncthreads();   // previous PV reads done before restaging
        // stage K (scaled, [c][ss]) and V (transposed, [ss][c])
        {
            const int cb = tid >> 4;
            const int s4 = (tid & 15) * 4;
            #pragma unroll
            for (int r = 0; r < 4; ++r) {
                const int c = cb + r * 16;
                float4 kv = *(const float4*)(kg + (size_t)c * NT + s0 + s4);
                kv.x *= scale; kv.y *= scale; kv.z *= scale; kv.w *= scale;
                *(float4*)&k_s[c * 68 + s4] = kv;
                float4 vv = *(const float4*)(vg + (size_t)c * NT + s0 + s4);
                vt_s[(s4 + 0) * 68 + c] = vv.x;
                vt_s[(s4 + 1) * 68 + c] = vv.y;
                vt_s[(s4 + 2) * 68 + c] = vv.z;
                vt_s[(s4 + 3) * 68 + c] = vv.w;
            }
        }
        __syncthreads();

        // S tile: S[4ty+i][4tx+j] = sum_c q_s[c][4ty+i] * k_s[c][4tx+j]
        float sacc[4][4] = {};
        #pragma unroll 8
        for (int c = 0; c < 64; ++c) {
            float a4[4], b4[4];
            *(float4*)a4 = *(const float4*)&q_s[c * 68 + ty * 4];
            *(float4*)b4 = *(const float4*)&k_s[c * 68 + tx * 4];
            #pragma unroll
            for (int i = 0; i < 4; ++i)
                #pragma unroll
                for (int j = 0; j < 4; ++j)
                    sacc[i][j] += a4[i] * b4[j];
        }

        // online softmax per row (rows 4ty+i; 16 threads tx share a row,
        // they sit in lanes [(ty&3)*16, +16) of one wave)
        float alpha[4];
        #pragma unroll
        for (int i = 0; i < 4; ++i) {
            float tm = fmaxf(fmaxf(sacc[i][0], sacc[i][1]),
                             fmaxf(sacc[i][2], sacc[i][3]));
            #pragma unroll
            for (int msk = 1; msk < 16; msk <<= 1)
                tm = fmaxf(tm, __shfl_xor(tm, msk, 64));
            const float mn = fmaxf(m_run[i], tm);
            alpha[i] = __expf(m_run[i] - mn);
            float rs = 0.f;
            #pragma unroll
            for (int j = 0; j < 4; ++j) {
                sacc[i][j] = __expf(sacc[i][j] - mn);
                rs += sacc[i][j];
            }
            #pragma unroll
            for (int msk = 1; msk < 16; msk <<= 1)
                rs += __shfl_xor(rs, msk, 64);
            l_run[i] = l_run[i] * alpha[i] + rs;
            m_run[i] = mn;
        }
        if (tx == 0) {
            #pragma unroll
            for (int i = 0; i < 4; ++i) alpha_s[ty * 4 + i] = alpha[i];
        }
        // write P transposed: p_s[ss][tt]; float4 over tt (i contiguous)
        #pragma unroll
        for (int j = 0; j < 4; ++j) {
            float4 pv;
            pv.x = sacc[0][j]; pv.y = sacc[1][j];
            pv.z = sacc[2][j]; pv.w = sacc[3][j];
            *(float4*)&p_s[(4 * tx + j) * 68 + 4 * ty] = pv;
        }
        __syncthreads();

        // PV: O[c=4ty+i][tt=4tx+j] = O*alpha[tt] + sum_ss vt_s[ss][c] * p_s[ss][tt]
        float aj[4];
        #pragma unroll
        for (int j = 0; j < 4; ++j) aj[j] = alpha_s[4 * tx + j];
        #pragma unroll
        for (int i = 0; i < 4; ++i)
            #pragma unroll
            for (int j = 0; j < 4; ++j)
                O[i][j] *= aj[j];
        #pragma unroll 8
        for (int ss = 0; ss < 64; ++ss) {
            float v4[4], p4[4];
            *(float4*)v4 = *(const float4*)&vt_s[ss * 68 + ty * 4];
            *(float4*)p4 = *(const float4*)&p_s[ss * 68 + tx * 4];
            #pragma unroll
            for (int i = 0; i < 4; ++i)
                #pragma unroll
                for (int j = 0; j < 4; ++j)
                    O[i][j] += v4[i] * p4[j];
        }
    }

    if (tx == 0) {
        #pragma unroll
        for (int i = 0; i < 4; ++i) l_s[ty * 4 + i] = l_run[i];
    }
    __syncthreads();
    float rl[4];
    #pragma unroll
    for (int j = 0; j < 4; ++j) rl[j] = 1.f / l_s[4 * tx + j];

    // out[b][hd*64 + c][t0 + tt], float4 over tt
    #pragma unroll
    for (int i = 0; i < 4; ++i) {
        const int c = 4 * ty + i;
        float4 o;
        o.x = O[i][0] * rl[0]; o.y = O[i][1] * rl[1];
        o.z = O[i][2] * rl[2]; o.w = O[i][3] * rl[3];
        *(float4*)(out + ((size_t)b * NC + hd * 64 + c) * NT + t0 + 4 * tx) = o;
    }
}

// ---------------------------------------------------------------------------
extern "C" void kernel_launch(void* const* d_in, const int* in_sizes, int n_in,
                              void* d_out, int out_size, void* d_ws, size_t ws_size,
                              hipStream_t stream)
{
    const float* x      = (const float*)d_in[0];
    const float* gn_w   = (const float*)d_in[1];
    const float* gn_b   = (const float*)d_in[2];
    const float* qkv_w  = (const float*)d_in[3];
    const float* qkv_b  = (const float*)d_in[4];
    const float* proj_w = (const float*)d_in[5];
    const float* proj_b = (const float*)d_in[6];
    float* out = (float*)d_out;

    // workspace: h [8*512*2048], qkv [8*1536*2048], attn [8*512*2048]
    float* h    = (float*)d_ws;
    float* qkv  = h + (size_t)NB * NC * NT;              // +8388608
    float* attn = qkv + (size_t)NB * 3 * NC * NT;        // +25165824

    // 1) GroupNorm -> h
    gn_kernel<<<NB * NG, 256, 0, stream>>>(x, gn_w, gn_b, h);

    // 2) qkv = qkv_w @ h + qkv_b   (M=1536, N=2048, K=512, batch=8)
    gemm_kernel<<<dim3(NT / 64, (3 * NC) / 64, NB), 256, 0, stream>>>(
        qkv_w, h, qkv_b, nullptr, qkv, 3 * NC, NT, NC);

    // 3) attention -> attn
    attn_kernel<<<dim3(NT / 64, NB * 8), 256, 0, stream>>>(qkv, attn);

    // 4) out = x + proj_w @ attn + proj_b   (M=512, N=2048, K=512, batch=8)
    gemm_kernel<<<dim3(NT / 64, NC / 64, NB), 256, 0, stream>>>(
        proj_w, attn, proj_b, x, out, NC, NT, NC);
}

// Round 2
// 854.580 us; speedup vs baseline: 1.9036x; 1.9036x over previous
//
#include <hip/hip_runtime.h>
#include <hip/hip_bf16.h>
#include <math.h>

// Problem constants: B=8, C=512, T=2048, G=32, HEADS=8, CH=64
#define NB 8
#define NC 512
#define NT 2048
#define NG 32

typedef __attribute__((ext_vector_type(8))) short short8;   // 8 bf16 (4 VGPRs)
typedef __attribute__((ext_vector_type(4))) float floatx4;  // MFMA 16x16 C/D

static __device__ __forceinline__ short f2bf(float f) {
    __hip_bfloat16 h = __float2bfloat16(f);
    return *reinterpret_cast<short*>(&h);
}

// ---------------------------------------------------------------------------
// Kernel 1: GroupNorm (unchanged from R1).
// ---------------------------------------------------------------------------
__global__ __launch_bounds__(256) void gn_kernel(
    const float* __restrict__ x, const float* __restrict__ gw,
    const float* __restrict__ gb, float* __restrict__ h)
{
    __shared__ float red[16];
    const int tid = threadIdx.x;
    const int grp = blockIdx.x;
    const int b = grp >> 5, gi = grp & 31;
    const size_t off = ((size_t)b * NC + gi * 16) * NT;
    const float4* xp = (const float4*)(x + off);
    float4* hp = (float4*)(h + off);

    float s = 0.f, ss = 0.f;
    for (int i = tid; i < 8192; i += 256) {
        float4 v = xp[i];
        s  += v.x + v.y + v.z + v.w;
        ss += v.x*v.x + v.y*v.y + v.z*v.z + v.w*v.w;
    }
    #pragma unroll
    for (int o = 32; o > 0; o >>= 1) {
        s  += __shfl_down(s,  o, 64);
        ss += __shfl_down(ss, o, 64);
    }
    const int lane = tid & 63, wid = tid >> 6;
    if (lane == 0) { red[wid] = s; red[8 + wid] = ss; }
    __syncthreads();
    if (tid == 0) {
        red[0] = red[0] + red[1] + red[2] + red[3];
        red[8] = red[8] + red[9] + red[10] + red[11];
    }
    __syncthreads();
    const float inv  = 1.f / 32768.f;
    const float mean = red[0] * inv;
    const float var  = red[8] * inv - mean * mean;
    const float rstd = rsqrtf(var + 1e-5f);

    for (int i = tid; i < 8192; i += 256) {
        const int c = gi * 16 + (i >> 9);
        const float wc = gw[c] * rstd;
        const float bc = gb[c] - mean * wc;
        float4 v = xp[i];
        v.x = v.x * wc + bc; v.y = v.y * wc + bc;
        v.z = v.z * wc + bc; v.w = v.w * wc + bc;
        hp[i] = v;
    }
}

// ---------------------------------------------------------------------------
// Kernel 2: batched fp32 GEMM (unchanged from R1).
// ---------------------------------------------------------------------------
__global__ __launch_bounds__(256) void gemm_kernel(
    const float* __restrict__ A, const float* __restrict__ Bm,
    const float* __restrict__ bias, const float* __restrict__ resid,
    float* __restrict__ Cm, int M, int N, int K)
{
    __shared__ __align__(16) float As[16][68];
    __shared__ __align__(16) float Bs[16][68];
    const int tid = threadIdx.x;
    const int tx = tid & 15, ty = tid >> 4;
    const int n0 = blockIdx.x * 64;
    const int m0 = blockIdx.y * 64;
    const int bz = blockIdx.z;
    const float* Bb = Bm + (size_t)bz * K * N;

    float acc[4][4] = {};
    const int am = tid >> 2;
    const int ak = (tid & 3) * 4;
    const int bk = tid >> 4;
    const int bn = (tid & 15) * 4;

    for (int k0 = 0; k0 < K; k0 += 16) {
        float4 av = *(const float4*)(A  + (size_t)(m0 + am) * K + k0 + ak);
        float4 bv = *(const float4*)(Bb + (size_t)(k0 + bk) * N + n0 + bn);
        As[ak + 0][am] = av.x; As[ak + 1][am] = av.y;
        As[ak + 2][am] = av.z; As[ak + 3][am] = av.w;
        *(float4*)&Bs[bk][bn] = bv;
        __syncthreads();
        #pragma unroll
        for (int kk = 0; kk < 16; ++kk) {
            float a4[4], b4[4];
            *(float4*)a4 = *(const float4*)&As[kk][ty * 4];
            *(float4*)b4 = *(const float4*)&Bs[kk][tx * 4];
            #pragma unroll
            for (int i = 0; i < 4; ++i)
                #pragma unroll
                for (int j = 0; j < 4; ++j)
                    acc[i][j] += a4[i] * b4[j];
        }
        __syncthreads();
    }

    for (int i = 0; i < 4; ++i) {
        const int m = m0 + ty * 4 + i;
        const float bv = bias[m];
        const size_t idx = (size_t)bz * M * N + (size_t)m * N + n0 + tx * 4;
        float4 o;
        o.x = acc[i][0] + bv; o.y = acc[i][1] + bv;
        o.z = acc[i][2] + bv; o.w = acc[i][3] + bv;
        if (resid) {
            float4 r = *(const float4*)(resid + idx);
            o.x += r.x; o.y += r.y; o.z += r.z; o.w += r.w;
        }
        *(float4*)(Cm + idx) = o;
    }
}

// ---------------------------------------------------------------------------
// Kernel 3: flash attention with bf16 MFMA (16x16x32).
// Block = 64 tt x 1 head-batch, 4 waves. Wave w owns tt strip [16w,16w+16).
// LDS (bf16, row stride 72 = 16B-aligned):
//   qt[tt][c] (Q^T, scaled, staged once)   -> A operand of S-phase
//   kt[ss][c] (K^T, scaled, per s-tile)    -> B operand of S-phase
//   vs[c][ss] (V natural, per s-tile)      -> B operand of PV-phase
//   ps[tt][ss] (P bf16, per-wave strip)    -> A operand of PV-phase
// C/D layout: col=lane&15, row=quad*4+reg  -> softmax rows reduce via
// 16-lane shfl_xor; online-softmax state in registers.
// ---------------------------------------------------------------------------
#define LSTR 72

__global__ __launch_bounds__(256) void attn_kernel(
    const float* __restrict__ qkv, float* __restrict__ out)
{
    __shared__ __align__(16) short qt[64 * LSTR];
    __shared__ __align__(16) short kt[64 * LSTR];
    __shared__ __align__(16) short vs[64 * LSTR];
    __shared__ __align__(16) short ps[64 * LSTR];

    const int tid  = threadIdx.x;
    const int wv   = tid >> 6;
    const int lane = tid & 63;
    const int l16  = lane & 15;
    const int quad = lane >> 4;
    const int t0 = blockIdx.x * 64;
    const int bh = blockIdx.y;
    const int b = bh >> 3, hd = bh & 7;
    const size_t base = ((size_t)b * (3 * NC) + hd * 64) * NT;
    const float* qg = qkv + base;
    const float* kg = qkv + base + (size_t)NC * NT;
    const float* vg = qkv + base + (size_t)(2 * NC) * NT;
    const float scale = 0.35355339059327373f;   // 64^-0.25

    const int sc = tid & 63;   // staging: channel
    const int sg = tid >> 6;   // staging: 16-wide s/t group

    // stage Q^T once: qt[tt][c], scaled
    {
        const float* src = qg + (size_t)sc * NT + t0 + sg * 16;
        #pragma unroll
        for (int i = 0; i < 4; ++i) {
            float4 v = *(const float4*)(src + i * 4);
            qt[(sg * 16 + i * 4 + 0) * LSTR + sc] = f2bf(v.x * scale);
            qt[(sg * 16 + i * 4 + 1) * LSTR + sc] = f2bf(v.y * scale);
            qt[(sg * 16 + i * 4 + 2) * LSTR + sc] = f2bf(v.z * scale);
            qt[(sg * 16 + i * 4 + 3) * LSTR + sc] = f2bf(v.w * scale);
        }
    }

    floatx4 O[4];
    #pragma unroll
    for (int nt = 0; nt < 4; ++nt) O[nt] = (floatx4){0.f, 0.f, 0.f, 0.f};
    float m_run[4], l_run[4];
    #pragma unroll
    for (int r = 0; r < 4; ++r) { m_run[r] = -1e30f; l_run[r] = 0.f; }

    for (int s0 = 0; s0 < NT; s0 += 64) {
        __syncthreads();   // prev iter's kt/vs reads done
        // stage K^T (scaled) and V (natural)
        {
            const float* ksrc = kg + (size_t)sc * NT + s0 + sg * 16;
            #pragma unroll
            for (int i = 0; i < 4; ++i) {
                float4 v = *(const float4*)(ksrc + i * 4);
                kt[(sg * 16 + i * 4 + 0) * LSTR + sc] = f2bf(v.x * scale);
                kt[(sg * 16 + i * 4 + 1) * LSTR + sc] = f2bf(v.y * scale);
                kt[(sg * 16 + i * 4 + 2) * LSTR + sc] = f2bf(v.z * scale);
                kt[(sg * 16 + i * 4 + 3) * LSTR + sc] = f2bf(v.w * scale);
            }
            const float* vsrc = vg + (size_t)sc * NT + s0 + sg * 16;
            __align__(16) short tmp[16];
            #pragma unroll
            for (int i = 0; i < 4; ++i) {
                float4 v = *(const float4*)(vsrc + i * 4);
                tmp[i * 4 + 0] = f2bf(v.x);
                tmp[i * 4 + 1] = f2bf(v.y);
                tmp[i * 4 + 2] = f2bf(v.z);
                tmp[i * 4 + 3] = f2bf(v.w);
            }
            *(short8*)&vs[sc * LSTR + sg * 16]     = *(const short8*)&tmp[0];
            *(short8*)&vs[sc * LSTR + sg * 16 + 8] = *(const short8*)&tmp[8];
        }
        __syncthreads();

        // ---- S-phase: S[tt][ss] = (Q^T K) -----------------------------
        floatx4 sacc[4];
        #pragma unroll
        for (int nt = 0; nt < 4; ++nt) sacc[nt] = (floatx4){0.f, 0.f, 0.f, 0.f};
        #pragma unroll
        for (int ks = 0; ks < 2; ++ks) {
            short8 aq = *(const short8*)&qt[(wv * 16 + l16) * LSTR + ks * 32 + quad * 8];
            #pragma unroll
            for (int nt = 0; nt < 4; ++nt) {
                short8 bk = *(const short8*)&kt[(nt * 16 + l16) * LSTR + ks * 32 + quad * 8];
                sacc[nt] = __builtin_amdgcn_mfma_f32_16x16x32_bf16(aq, bk, sacc[nt], 0, 0, 0);
            }
        }

        // ---- online softmax (rows tt = wv*16 + quad*4 + r) ------------
        float alpha[4];
        #pragma unroll
        for (int r = 0; r < 4; ++r) {
            float tm = fmaxf(fmaxf(sacc[0][r], sacc[1][r]),
                             fmaxf(sacc[2][r], sacc[3][r]));
            #pragma unroll
            for (int msk = 1; msk < 16; msk <<= 1)
                tm = fmaxf(tm, __shfl_xor(tm, msk, 64));
            const float mn = fmaxf(m_run[r], tm);
            alpha[r] = __expf(m_run[r] - mn);
            float rs = 0.f;
            #pragma unroll
            for (int nt = 0; nt < 4; ++nt) {
                const float p = __expf(sacc[nt][r] - mn);
                sacc[nt][r] = p;
                rs += p;
            }
            #pragma unroll
            for (int msk = 1; msk < 16; msk <<= 1)
                rs += __shfl_xor(rs, msk, 64);
            l_run[r] = l_run[r] * alpha[r] + rs;
            m_run[r] = mn;
        }

        // write P (bf16) to per-wave strip of ps[tt][ss]; rescale O
        #pragma unroll
        for (int nt = 0; nt < 4; ++nt) {
            #pragma unroll
            for (int r = 0; r < 4; ++r) {
                ps[(wv * 16 + quad * 4 + r) * LSTR + nt * 16 + l16] = f2bf(sacc[nt][r]);
                O[nt][r] *= alpha[r];
            }
        }
        // no barrier needed: ps strip is wave-private, DS pipe in-order

        // ---- PV-phase: O^T[tt][c] += P V^T ----------------------------
        #pragma unroll
        for (int ks = 0; ks < 2; ++ks) {
            short8 ap = *(const short8*)&ps[(wv * 16 + l16) * LSTR + ks * 32 + quad * 8];
            #pragma unroll
            for (int nt = 0; nt < 4; ++nt) {
                short8 bv = *(const short8*)&vs[(nt * 16 + l16) * LSTR + ks * 32 + quad * 8];
                O[nt] = __builtin_amdgcn_mfma_f32_16x16x32_bf16(ap, bv, O[nt], 0, 0, 0);
            }
        }
    }

    // epilogue: normalize by l, write attn[b][hd*64 + c][t0 + tt]
    float rl[4];
    #pragma unroll
    for (int r = 0; r < 4; ++r) rl[r] = 1.f / l_run[r];
    float* outb = out + ((size_t)b * NC + hd * 64) * NT + t0;
    #pragma unroll
    for (int nt = 0; nt < 4; ++nt) {
        #pragma unroll
        for (int r = 0; r < 4; ++r) {
            outb[(size_t)(nt * 16 + l16) * NT + wv * 16 + quad * 4 + r] = O[nt][r] * rl[r];
        }
    }
}

// ---------------------------------------------------------------------------
extern "C" void kernel_launch(void* const* d_in, const int* in_sizes, int n_in,
                              void* d_out, int out_size, void* d_ws, size_t ws_size,
                              hipStream_t stream)
{
    const float* x      = (const float*)d_in[0];
    const float* gn_w   = (const float*)d_in[1];
    const float* gn_b   = (const float*)d_in[2];
    const float* qkv_w  = (const float*)d_in[3];
    const float* qkv_b  = (const float*)d_in[4];
    const float* proj_w = (const float*)d_in[5];
    const float* proj_b = (const float*)d_in[6];
    float* out = (float*)d_out;

    float* h    = (float*)d_ws;
    float* qkv  = h + (size_t)NB * NC * NT;
    float* attn = qkv + (size_t)NB * 3 * NC * NT;

    gn_kernel<<<NB * NG, 256, 0, stream>>>(x, gn_w, gn_b, h);

    gemm_kernel<<<dim3(NT / 64, (3 * NC) / 64, NB), 256, 0, stream>>>(
        qkv_w, h, qkv_b, nullptr, qkv, 3 * NC, NT, NC);

    attn_kernel<<<dim3(NT / 64, NB * 8), 256, 0, stream>>>(qkv, attn);

    gemm_kernel<<<dim3(NT / 64, NC / 64, NB), 256, 0, stream>>>(
        proj_w, attn, proj_b, x, out, NC, NT, NC);
}

// Round 3
// 327.751 us; speedup vs baseline: 4.9634x; 2.6074x over previous
//
#include <hip/hip_runtime.h>
#include <hip/hip_bf16.h>
#include <math.h>

// Problem constants: B=8, C=512, T=2048, G=32, HEADS=8, CH=64
#define NB 8
#define NC 512
#define NT 2048
#define NG 32
#define NH 8
#define CH 64

typedef __attribute__((ext_vector_type(8))) short short8;   // 8 bf16
typedef __attribute__((ext_vector_type(4))) short short4v;  // 4 bf16 (8B)
typedef __attribute__((ext_vector_type(4))) float floatx4;  // MFMA C/D

static __device__ __forceinline__ short f2bf(float f) {
    __hip_bfloat16 h = __float2bfloat16(f);
    return *reinterpret_cast<short*>(&h);
}

static __device__ __forceinline__ void gload_lds16(const short* g, short* l) {
    __builtin_amdgcn_global_load_lds(
        (const __attribute__((address_space(1))) void*)g,
        (__attribute__((address_space(3))) void*)l, 16, 0, 0);
}

// ---------------------------------------------------------------------------
// fp32 -> bf16 cast (weights)
// ---------------------------------------------------------------------------
__global__ __launch_bounds__(256) void castw_kernel(
    const float* __restrict__ w, short* __restrict__ o, int n4)
{
    const int i = blockIdx.x * 256 + threadIdx.x;
    if (i < n4) {
        float4 v = ((const float4*)w)[i];
        short4v s;
        s.x = f2bf(v.x); s.y = f2bf(v.y); s.z = f2bf(v.z); s.w = f2bf(v.w);
        *(short4v*)&o[i * 4] = s;
    }
}

// ---------------------------------------------------------------------------
// GroupNorm stats: one block per (b,g); group = 16ch x 2048t contiguous.
// ---------------------------------------------------------------------------
__global__ __launch_bounds__(256) void gn_stats_kernel(
    const float* __restrict__ x, float* __restrict__ stats)
{
    __shared__ float red[16];
    const int tid = threadIdx.x;
    const int grp = blockIdx.x;
    const float4* xp = (const float4*)(x + (size_t)grp * 16 * NT);

    float s = 0.f, ss = 0.f;
    for (int i = tid; i < 8192; i += 256) {
        float4 v = xp[i];
        s  += v.x + v.y + v.z + v.w;
        ss += v.x*v.x + v.y*v.y + v.z*v.z + v.w*v.w;
    }
    #pragma unroll
    for (int o = 32; o > 0; o >>= 1) {
        s  += __shfl_down(s,  o, 64);
        ss += __shfl_down(ss, o, 64);
    }
    const int lane = tid & 63, wid = tid >> 6;
    if (lane == 0) { red[wid] = s; red[8 + wid] = ss; }
    __syncthreads();
    if (tid == 0) {
        const float inv = 1.f / 32768.f;
        const float mean = (red[0] + red[1] + red[2] + red[3]) * inv;
        const float var  = (red[8] + red[9] + red[10] + red[11]) * inv - mean * mean;
        stats[grp * 2]     = mean;
        stats[grp * 2 + 1] = rsqrtf(var + 1e-5f);
    }
}

// ---------------------------------------------------------------------------
// GroupNorm apply + transpose + bf16: h_t[b][t][c]. Block = (t-tile 64, b).
// Thread: t = t0 + tid/4, covers c in interleaved chunks of 8 (16B stores).
// ---------------------------------------------------------------------------
__global__ __launch_bounds__(256) void gn_apply_kernel(
    const float* __restrict__ x, const float* __restrict__ gw,
    const float* __restrict__ gb, const float* __restrict__ stats,
    short* __restrict__ ht)
{
    __shared__ float wc_s[NC], bc_s[NC];
    const int tid = threadIdx.x;
    const int b = blockIdx.y;
    const int t0 = blockIdx.x * 64;

    for (int c = tid; c < NC; c += 256) {
        const int g = c >> 4;
        const float mean = stats[(b * NG + g) * 2];
        const float rstd = stats[(b * NG + g) * 2 + 1];
        const float wc = gw[c] * rstd;
        wc_s[c] = wc;
        bc_s[c] = gb[c] - mean * wc;
    }
    __syncthreads();

    const int t  = t0 + (tid >> 2);
    const int lc = tid & 3;
    const float* xb = x + (size_t)b * NC * NT + t;
    short* out = ht + ((size_t)b * NT + t) * NC;

    for (int k = 0; k < 16; ++k) {
        const int c0 = lc * 8 + k * 32;
        short8 v;
        #pragma unroll
        for (int j = 0; j < 8; ++j) {
            const int c = c0 + j;
            v[j] = f2bf(xb[(size_t)c * NT] * wc_s[c] + bc_s[c]);
        }
        *(short8*)&out[c0] = v;
    }
}

// ---------------------------------------------------------------------------
// QKV GEMM, m97-style bf16 MFMA. D[m=o][n=t] = sum_c w[o][c] * h_t[t][c].
// 128x128 tile, BK=32, 256 thr. global_load_lds(16B) staging (no transposes).
// Epilogue: o<1024 -> q_t/k_t[bh][t][64] bf16 scaled (dwordx2);
//           o>=1024 -> v[bh][64][t] bf16 natural (2B stores, 32B runs).
// ---------------------------------------------------------------------------
#define BK 32
__global__ __launch_bounds__(256) void qkv_gemm_kernel(
    const short* __restrict__ wb,   // [1536][512] bf16
    const short* __restrict__ ht,   // [16384][512] bf16
    const float* __restrict__ bias, // [1536]
    short* __restrict__ q_t, short* __restrict__ k_t, short* __restrict__ vv)
{
    __shared__ short As[128 * BK];
    __shared__ short Bs[128 * BK];
    const int tid = threadIdx.x;
    const int wv = tid >> 6, lane = tid & 63;
    const int l16 = lane & 15, quad = lane >> 4;
    const int n0 = blockIdx.x * 128;   // t tile
    const int m0 = blockIdx.y * 128;   // o tile
    const int wm = wv & 1, wn = wv >> 1;

    floatx4 acc[4][4];
    #pragma unroll
    for (int i = 0; i < 4; ++i)
        #pragma unroll
        for (int j = 0; j < 4; ++j) acc[i][j] = (floatx4){0.f, 0.f, 0.f, 0.f};

    const short* gsrc = (wv < 2) ? wb : ht;
    const int rbase = (wv & 1) * 64;
    const int tile0 = (wv < 2) ? m0 : n0;
    short* lbuf = (wv < 2) ? As : Bs;
    const int lrow = lane >> 2;          // 0..15 within chunk
    const int lcol = (lane & 3) * 8;     // shorts

    for (int k0 = 0; k0 < 512; k0 += BK) {
        __syncthreads();
        #pragma unroll
        for (int ch = 0; ch < 4; ++ch) {
            const int row = rbase + ch * 16 + lrow;
            gload_lds16(gsrc + (size_t)(tile0 + row) * 512 + k0 + lcol,
                        lbuf + (rbase + ch * 16) * BK);
        }
        __syncthreads();

        short8 af[4], bf[4];
        #pragma unroll
        for (int i = 0; i < 4; ++i) {
            af[i] = *(const short8*)&As[(wm * 64 + i * 16 + l16) * BK + quad * 8];
            bf[i] = *(const short8*)&Bs[(wn * 64 + i * 16 + l16) * BK + quad * 8];
        }
        #pragma unroll
        for (int i = 0; i < 4; ++i)
            #pragma unroll
            for (int j = 0; j < 4; ++j)
                acc[i][j] = __builtin_amdgcn_mfma_f32_16x16x32_bf16(
                    af[i], bf[j], acc[i][j], 0, 0, 0);
    }

    const float qscale = 0.35355339059327373f;   // 64^-0.25
    #pragma unroll
    for (int i = 0; i < 4; ++i) {
        const int o16 = m0 + wm * 64 + i * 16;   // 16-aligned, one (sel,h) per wave-i
        const int sel = o16 >> 9;
        const int hh  = (o16 >> 6) & 7;
        const int c16 = o16 & 63;
        const float4 b4 = *(const float4*)&bias[o16 + quad * 4];
        #pragma unroll
        for (int j = 0; j < 4; ++j) {
            const int tg = n0 + wn * 64 + j * 16 + l16;
            const int b = tg >> 11, t = tg & 2047;
            floatx4 v = acc[i][j];
            v[0] += b4.x; v[1] += b4.y; v[2] += b4.z; v[3] += b4.w;
            if (sel < 2) {
                short4v s;
                s.x = f2bf(v[0] * qscale); s.y = f2bf(v[1] * qscale);
                s.z = f2bf(v[2] * qscale); s.w = f2bf(v[3] * qscale);
                short* dst = (sel == 0 ? q_t : k_t) +
                    (((size_t)(b * NH + hh) * NT + t) * CH + c16 + quad * 4);
                *(short4v*)dst = s;
            } else {
                short* dst = vv + ((size_t)(b * NH + hh) * CH + c16 + quad * 4) * NT + t;
                #pragma unroll
                for (int r = 0; r < 4; ++r) dst[(size_t)r * NT] = f2bf(v[r]);
            }
        }
    }
}

// ---------------------------------------------------------------------------
// Flash attention v3. Inputs pre-scaled bf16: q_t/k_t[bh][t][64], v[bh][64][t].
// Block = 64 tt x 1 bh, 4 waves; wave owns tt strip [wv*16,+16).
// S swapped: A=K rows ss, B=Q rows tt -> D[ss][tt]; softmax per lane
// (row tt = wv*16+l16) mostly in-register + 2 quad shuffles.
// PV swapped: A=V rows c, B=P rows tt -> D[c][tt] -> dwordx2 stores to
// attn_t[b][t][512] (proj's B-operand layout).
// ---------------------------------------------------------------------------
#define LSTR 72
__global__ __launch_bounds__(256) void attn_kernel(
    const short* __restrict__ qg, const short* __restrict__ kg,
    const short* __restrict__ vg, short* __restrict__ at)
{
    __shared__ short qt_s[64 * LSTR];
    __shared__ short kt_s[64 * LSTR];
    __shared__ short vs_s[64 * LSTR];
    __shared__ short ps_s[64 * LSTR];

    const int tid = threadIdx.x;
    const int wv = tid >> 6, lane = tid & 63;
    const int l16 = lane & 15, quad = lane >> 4;
    const int t0 = blockIdx.x * 64;
    const int bh = blockIdx.y;
    const short* qh = qg + (size_t)bh * NT * CH;
    const short* kh = kg + (size_t)bh * NT * CH;
    const short* vh = vg + (size_t)bh * CH * NT;

    const int srow = tid >> 2;            // 0..63
    const int sseg = (tid & 3) * 16;      // 0,16,32,48 shorts

    // stage Q strip once: qt_s[tt][c]
    *(short8*)&qt_s[srow * LSTR + sseg] =
        *(const short8*)&qh[(size_t)(t0 + srow) * CH + sseg];
    *(short8*)&qt_s[srow * LSTR + sseg + 8] =
        *(const short8*)&qh[(size_t)(t0 + srow) * CH + sseg + 8];

    floatx4 Oa[4];
    #pragma unroll
    for (int nt = 0; nt < 4; ++nt) Oa[nt] = (floatx4){0.f, 0.f, 0.f, 0.f};
    float m_run = -1e30f, l_run = 0.f;

    for (int s0 = 0; s0 < NT; s0 += 64) {
        __syncthreads();   // prev iter frag reads done
        // stage K rows (ss) and V rows (c) — pure wide copies
        *(short8*)&kt_s[srow * LSTR + sseg] =
            *(const short8*)&kh[(size_t)(s0 + srow) * CH + sseg];
        *(short8*)&kt_s[srow * LSTR + sseg + 8] =
            *(const short8*)&kh[(size_t)(s0 + srow) * CH + sseg + 8];
        *(short8*)&vs_s[srow * LSTR + sseg] =
            *(const short8*)&vh[(size_t)srow * NT + s0 + sseg];
        *(short8*)&vs_s[srow * LSTR + sseg + 8] =
            *(const short8*)&vh[(size_t)srow * NT + s0 + sseg + 8];
        __syncthreads();

        // ---- S: D[m=ss][n=tt] ----
        floatx4 sacc[4];
        #pragma unroll
        for (int nt = 0; nt < 4; ++nt) sacc[nt] = (floatx4){0.f, 0.f, 0.f, 0.f};
        short8 bq0 = *(const short8*)&qt_s[(wv * 16 + l16) * LSTR + quad * 8];
        short8 bq1 = *(const short8*)&qt_s[(wv * 16 + l16) * LSTR + 32 + quad * 8];
        #pragma unroll
        for (int nt = 0; nt < 4; ++nt) {
            short8 ak0 = *(const short8*)&kt_s[(nt * 16 + l16) * LSTR + quad * 8];
            short8 ak1 = *(const short8*)&kt_s[(nt * 16 + l16) * LSTR + 32 + quad * 8];
            sacc[nt] = __builtin_amdgcn_mfma_f32_16x16x32_bf16(ak0, bq0, sacc[nt], 0, 0, 0);
            sacc[nt] = __builtin_amdgcn_mfma_f32_16x16x32_bf16(ak1, bq1, sacc[nt], 0, 0, 0);
        }

        // ---- online softmax: lane owns row tt = wv*16+l16 ----
        float tm = -1e30f;
        #pragma unroll
        for (int nt = 0; nt < 4; ++nt)
            #pragma unroll
            for (int r = 0; r < 4; ++r) tm = fmaxf(tm, sacc[nt][r]);
        tm = fmaxf(tm, __shfl_xor(tm, 16, 64));
        tm = fmaxf(tm, __shfl_xor(tm, 32, 64));
        const float mn = fmaxf(m_run, tm);
        const float alpha = __expf(m_run - mn);
        float rs = 0.f;
        #pragma unroll
        for (int nt = 0; nt < 4; ++nt)
            #pragma unroll
            for (int r = 0; r < 4; ++r) {
                const float p = __expf(sacc[nt][r] - mn);
                sacc[nt][r] = p;
                rs += p;
            }
        rs += __shfl_xor(rs, 16, 64);
        rs += __shfl_xor(rs, 32, 64);
        l_run = l_run * alpha + rs;
        m_run = mn;

        // P -> ps_s[tt][ss] (wave-private strip; 8B packed stores)
        #pragma unroll
        for (int nt = 0; nt < 4; ++nt) {
            short4v s;
            s.x = f2bf(sacc[nt][0]); s.y = f2bf(sacc[nt][1]);
            s.z = f2bf(sacc[nt][2]); s.w = f2bf(sacc[nt][3]);
            *(short4v*)&ps_s[(wv * 16 + l16) * LSTR + nt * 16 + quad * 4] = s;
            Oa[nt][0] *= alpha; Oa[nt][1] *= alpha;
            Oa[nt][2] *= alpha; Oa[nt][3] *= alpha;
        }
        // no barrier: strip written & read by this wave only; DS in-order

        // ---- PV: D[m=c][n=tt] ----
        short8 bp0 = *(const short8*)&ps_s[(wv * 16 + l16) * LSTR + quad * 8];
        short8 bp1 = *(const short8*)&ps_s[(wv * 16 + l16) * LSTR + 32 + quad * 8];
        #pragma unroll
        for (int nt = 0; nt < 4; ++nt) {
            short8 av0 = *(const short8*)&vs_s[(nt * 16 + l16) * LSTR + quad * 8];
            short8 av1 = *(const short8*)&vs_s[(nt * 16 + l16) * LSTR + 32 + quad * 8];
            Oa[nt] = __builtin_amdgcn_mfma_f32_16x16x32_bf16(av0, bp0, Oa[nt], 0, 0, 0);
            Oa[nt] = __builtin_amdgcn_mfma_f32_16x16x32_bf16(av1, bp1, Oa[nt], 0, 0, 0);
        }
    }

    // epilogue: attn_t[b][t][hd*64 + c], c 4-consecutive per lane
    const float rl = 1.f / l_run;
    const int b = bh >> 3, hd = bh & 7;
    short* dst = at + ((size_t)b * NT + t0 + wv * 16 + l16) * NC + hd * CH;
    #pragma unroll
    for (int nt = 0; nt < 4; ++nt) {
        short4v s;
        s.x = f2bf(Oa[nt][0] * rl); s.y = f2bf(Oa[nt][1] * rl);
        s.z = f2bf(Oa[nt][2] * rl); s.w = f2bf(Oa[nt][3] * rl);
        *(short4v*)&dst[nt * 16 + quad * 4] = s;
    }
}

// ---------------------------------------------------------------------------
// Proj GEMM + bias + residual. D[m=o][n=t] = sum_c pw[o][c] * attn_t[t][c].
// Same m97 structure; fp32 epilogue, 64B-coalesced scalar stores.
// ---------------------------------------------------------------------------
__global__ __launch_bounds__(256) void proj_gemm_kernel(
    const short* __restrict__ wb,   // [512][512] bf16
    const short* __restrict__ at,   // [16384][512] bf16
    const float* __restrict__ bias, // [512]
    const float* __restrict__ xres, // [8][512][2048]
    float* __restrict__ out)
{
    __shared__ short As[128 * BK];
    __shared__ short Bs[128 * BK];
    const int tid = threadIdx.x;
    const int wv = tid >> 6, lane = tid & 63;
    const int l16 = lane & 15, quad = lane >> 4;
    const int n0 = blockIdx.x * 128;   // t
    const int m0 = blockIdx.y * 128;   // o
    const int wm = wv & 1, wn = wv >> 1;

    floatx4 acc[4][4];
    #pragma unroll
    for (int i = 0; i < 4; ++i)
        #pragma unroll
        for (int j = 0; j < 4; ++j) acc[i][j] = (floatx4){0.f, 0.f, 0.f, 0.f};

    const short* gsrc = (wv < 2) ? wb : at;
    const int rbase = (wv & 1) * 64;
    const int tile0 = (wv < 2) ? m0 : n0;
    short* lbuf = (wv < 2) ? As : Bs;
    const int lrow = lane >> 2;
    const int lcol = (lane & 3) * 8;

    for (int k0 = 0; k0 < 512; k0 += BK) {
        __syncthreads();
        #pragma unroll
        for (int ch = 0; ch < 4; ++ch) {
            const int row = rbase + ch * 16 + lrow;
            gload_lds16(gsrc + (size_t)(tile0 + row) * 512 + k0 + lcol,
                        lbuf + (rbase + ch * 16) * BK);
        }
        __syncthreads();

        short8 af[4], bf[4];
        #pragma unroll
        for (int i = 0; i < 4; ++i) {
            af[i] = *(const short8*)&As[(wm * 64 + i * 16 + l16) * BK + quad * 8];
            bf[i] = *(const short8*)&Bs[(wn * 64 + i * 16 + l16) * BK + quad * 8];
        }
        #pragma unroll
        for (int i = 0; i < 4; ++i)
            #pragma unroll
            for (int j = 0; j < 4; ++j)
                acc[i][j] = __builtin_amdgcn_mfma_f32_16x16x32_bf16(
                    af[i], bf[j], acc[i][j], 0, 0, 0);
    }

    #pragma unroll
    for (int i = 0; i < 4; ++i) {
        const int o16 = m0 + wm * 64 + i * 16;
        const float4 b4 = *(const float4*)&bias[o16 + quad * 4];
        #pragma unroll
        for (int j = 0; j < 4; ++j) {
            const int tg = n0 + wn * 64 + j * 16 + l16;
            const int b = tg >> 11, t = tg & 2047;
            const size_t base = ((size_t)b * NC + o16 + quad * 4) * NT + t;
            floatx4 v = acc[i][j];
            out[base]          = v[0] + b4.x + xres[base];
            out[base + NT]     = v[1] + b4.y + xres[base + NT];
            out[base + 2 * NT] = v[2] + b4.z + xres[base + 2 * NT];
            out[base + 3 * NT] = v[3] + b4.w + xres[base + 3 * NT];
        }
    }
}

// ---------------------------------------------------------------------------
extern "C" void kernel_launch(void* const* d_in, const int* in_sizes, int n_in,
                              void* d_out, int out_size, void* d_ws, size_t ws_size,
                              hipStream_t stream)
{
    const float* x      = (const float*)d_in[0];
    const float* gn_w   = (const float*)d_in[1];
    const float* gn_b   = (const float*)d_in[2];
    const float* qkv_w  = (const float*)d_in[3];
    const float* qkv_b  = (const float*)d_in[4];
    const float* proj_w = (const float*)d_in[5];
    const float* proj_b = (const float*)d_in[6];
    float* out = (float*)d_out;

    // workspace layout (shorts unless noted)
    short* ht  = (short*)d_ws;            // [8*2048][512]        8388608
    short* q_t = ht  + 8388608;           // [64][2048][64]       8388608
    short* k_t = q_t + 8388608;           //                      8388608
    short* vv  = k_t + 8388608;           // [64][64][2048]       8388608
    short* at  = vv  + 8388608;           // [8*2048][512]        8388608
    short* qwb = at  + 8388608;           // [1536][512]           786432
    short* pwb = qwb + 786432;            // [512][512]            262144
    float* stats = (float*)(pwb + 262144);// [256][2] fp32

    castw_kernel<<<768, 256, 0, stream>>>(qkv_w, qwb, 1536 * 512 / 4);
    castw_kernel<<<256, 256, 0, stream>>>(proj_w, pwb, 512 * 512 / 4);
    gn_stats_kernel<<<NB * NG, 256, 0, stream>>>(x, stats);
    gn_apply_kernel<<<dim3(NT / 64, NB), 256, 0, stream>>>(x, gn_w, gn_b, stats, ht);
    qkv_gemm_kernel<<<dim3(128, 12), 256, 0, stream>>>(qwb, ht, qkv_b, q_t, k_t, vv);
    attn_kernel<<<dim3(NT / 64, NB * NH), 256, 0, stream>>>(q_t, k_t, vv, at);
    proj_gemm_kernel<<<dim3(128, 4), 256, 0, stream>>>(pwb, at, proj_b, x, out);
}

// Round 4
// 314.278 us; speedup vs baseline: 5.1762x; 1.0429x over previous
//
#include <hip/hip_runtime.h>
#include <hip/hip_bf16.h>
#include <math.h>

// Problem constants: B=8, C=512, T=2048, G=32, HEADS=8, CH=64
#define NB 8
#define NC 512
#define NT 2048
#define NG 32
#define NH 8
#define CH 64

typedef __attribute__((ext_vector_type(8))) short short8;   // 8 bf16
typedef __attribute__((ext_vector_type(4))) short short4v;  // 4 bf16 (8B)
typedef __attribute__((ext_vector_type(4))) float floatx4;  // MFMA C/D

static __device__ __forceinline__ short f2bf(float f) {
    __hip_bfloat16 h = __float2bfloat16(f);
    return *reinterpret_cast<short*>(&h);
}

// RNE float->bf16 without NaN check (values are finite here)
static __device__ __forceinline__ short rne_bf16(float f) {
    unsigned u = __builtin_bit_cast(unsigned, f);
    u += 0x7FFF + ((u >> 16) & 1);
    return (short)(u >> 16);
}

static __device__ __forceinline__ void gload_lds16(const short* g, short* l) {
    __builtin_amdgcn_global_load_lds(
        (const __attribute__((address_space(1))) void*)g,
        (__attribute__((address_space(3))) void*)l, 16, 0, 0);
}

// ---------------------------------------------------------------------------
// fp32 -> bf16 cast (weights)
// ---------------------------------------------------------------------------
__global__ __launch_bounds__(256) void castw_kernel(
    const float* __restrict__ w, short* __restrict__ o, int n4)
{
    const int i = blockIdx.x * 256 + threadIdx.x;
    if (i < n4) {
        float4 v = ((const float4*)w)[i];
        short4v s;
        s.x = f2bf(v.x); s.y = f2bf(v.y); s.z = f2bf(v.z); s.w = f2bf(v.w);
        *(short4v*)&o[i * 4] = s;
    }
}

// ---------------------------------------------------------------------------
// GroupNorm stats
// ---------------------------------------------------------------------------
__global__ __launch_bounds__(256) void gn_stats_kernel(
    const float* __restrict__ x, float* __restrict__ stats)
{
    __shared__ float red[16];
    const int tid = threadIdx.x;
    const int grp = blockIdx.x;
    const float4* xp = (const float4*)(x + (size_t)grp * 16 * NT);

    float s = 0.f, ss = 0.f;
    for (int i = tid; i < 8192; i += 256) {
        float4 v = xp[i];
        s  += v.x + v.y + v.z + v.w;
        ss += v.x*v.x + v.y*v.y + v.z*v.z + v.w*v.w;
    }
    #pragma unroll
    for (int o = 32; o > 0; o >>= 1) {
        s  += __shfl_down(s,  o, 64);
        ss += __shfl_down(ss, o, 64);
    }
    const int lane = tid & 63, wid = tid >> 6;
    if (lane == 0) { red[wid] = s; red[8 + wid] = ss; }
    __syncthreads();
    if (tid == 0) {
        const float inv = 1.f / 32768.f;
        const float mean = (red[0] + red[1] + red[2] + red[3]) * inv;
        const float var  = (red[8] + red[9] + red[10] + red[11]) * inv - mean * mean;
        stats[grp * 2]     = mean;
        stats[grp * 2 + 1] = rsqrtf(var + 1e-5f);
    }
}

// ---------------------------------------------------------------------------
// GroupNorm apply + transpose + bf16: h_t[b][t][c]
// ---------------------------------------------------------------------------
__global__ __launch_bounds__(256) void gn_apply_kernel(
    const float* __restrict__ x, const float* __restrict__ gw,
    const float* __restrict__ gb, const float* __restrict__ stats,
    short* __restrict__ ht)
{
    __shared__ float wc_s[NC], bc_s[NC];
    const int tid = threadIdx.x;
    const int b = blockIdx.y;
    const int t0 = blockIdx.x * 64;

    for (int c = tid; c < NC; c += 256) {
        const int g = c >> 4;
        const float mean = stats[(b * NG + g) * 2];
        const float rstd = stats[(b * NG + g) * 2 + 1];
        const float wc = gw[c] * rstd;
        wc_s[c] = wc;
        bc_s[c] = gb[c] - mean * wc;
    }
    __syncthreads();

    const int t  = t0 + (tid >> 2);
    const int lc = tid & 3;
    const float* xb = x + (size_t)b * NC * NT + t;
    short* out = ht + ((size_t)b * NT + t) * NC;

    for (int k = 0; k < 16; ++k) {
        const int c0 = lc * 8 + k * 32;
        short8 v;
        #pragma unroll
        for (int j = 0; j < 8; ++j) {
            const int c = c0 + j;
            v[j] = f2bf(xb[(size_t)c * NT] * wc_s[c] + bc_s[c]);
        }
        *(short8*)&out[c0] = v;
    }
}

// ---------------------------------------------------------------------------
// QKV GEMM (m97-style). Epilogue: q gets scale*log2e (exp2 softmax),
// k gets scale; v natural layout.
// ---------------------------------------------------------------------------
#define BK 32
__global__ __launch_bounds__(256) void qkv_gemm_kernel(
    const short* __restrict__ wb, const short* __restrict__ ht,
    const float* __restrict__ bias,
    short* __restrict__ q_t, short* __restrict__ k_t, short* __restrict__ vv)
{
    __shared__ short As[128 * BK];
    __shared__ short Bs[128 * BK];
    const int tid = threadIdx.x;
    const int wv = tid >> 6, lane = tid & 63;
    const int l16 = lane & 15, quad = lane >> 4;
    const int n0 = blockIdx.x * 128;
    const int m0 = blockIdx.y * 128;
    const int wm = wv & 1, wn = wv >> 1;

    floatx4 acc[4][4];
    #pragma unroll
    for (int i = 0; i < 4; ++i)
        #pragma unroll
        for (int j = 0; j < 4; ++j) acc[i][j] = (floatx4){0.f, 0.f, 0.f, 0.f};

    const short* gsrc = (wv < 2) ? wb : ht;
    const int rbase = (wv & 1) * 64;
    const int tile0 = (wv < 2) ? m0 : n0;
    short* lbuf = (wv < 2) ? As : Bs;
    const int lrow = lane >> 2;
    const int lcol = (lane & 3) * 8;

    for (int k0 = 0; k0 < 512; k0 += BK) {
        __syncthreads();
        #pragma unroll
        for (int ch = 0; ch < 4; ++ch) {
            const int row = rbase + ch * 16 + lrow;
            gload_lds16(gsrc + (size_t)(tile0 + row) * 512 + k0 + lcol,
                        lbuf + (rbase + ch * 16) * BK);
        }
        __syncthreads();

        short8 af[4], bfr[4];
        #pragma unroll
        for (int i = 0; i < 4; ++i) {
            af[i]  = *(const short8*)&As[(wm * 64 + i * 16 + l16) * BK + quad * 8];
            bfr[i] = *(const short8*)&Bs[(wn * 64 + i * 16 + l16) * BK + quad * 8];
        }
        #pragma unroll
        for (int i = 0; i < 4; ++i)
            #pragma unroll
            for (int j = 0; j < 4; ++j)
                acc[i][j] = __builtin_amdgcn_mfma_f32_16x16x32_bf16(
                    af[i], bfr[j], acc[i][j], 0, 0, 0);
    }

    const float kscale = 0.35355339059327373f;              // 64^-0.25
    const float qscale = 0.35355339059327373f * 1.4426950408889634f; // * log2(e)
    #pragma unroll
    for (int i = 0; i < 4; ++i) {
        const int o16 = m0 + wm * 64 + i * 16;
        const int sel = o16 >> 9;
        const int hh  = (o16 >> 6) & 7;
        const int c16 = o16 & 63;
        const float4 b4 = *(const float4*)&bias[o16 + quad * 4];
        const float sc = (sel == 0) ? qscale : kscale;
        #pragma unroll
        for (int j = 0; j < 4; ++j) {
            const int tg = n0 + wn * 64 + j * 16 + l16;
            const int b = tg >> 11, t = tg & 2047;
            floatx4 v = acc[i][j];
            v[0] += b4.x; v[1] += b4.y; v[2] += b4.z; v[3] += b4.w;
            if (sel < 2) {
                short4v s;
                s.x = f2bf(v[0] * sc); s.y = f2bf(v[1] * sc);
                s.z = f2bf(v[2] * sc); s.w = f2bf(v[3] * sc);
                short* dst = (sel == 0 ? q_t : k_t) +
                    (((size_t)(b * NH + hh) * NT + t) * CH + c16 + quad * 4);
                *(short4v*)dst = s;
            } else {
                short* dst = vv + ((size_t)(b * NH + hh) * CH + c16 + quad * 4) * NT + t;
                #pragma unroll
                for (int r = 0; r < 4; ++r) dst[(size_t)r * NT] = f2bf(v[r]);
            }
        }
    }
}

// ---------------------------------------------------------------------------
// Flash attention v4. Block = 128 tt x 1 bh, 4 waves; wave owns 2 strips of
// 16 tt. XOR-swizzled pad-free LDS (chunk' = chunk ^ (row&7), 16B granules):
// conflict-free frag access AND global_load_lds(16B) staging. K/V double-
// buffered, 1 barrier/tile, prefetch overlaps compute. No-max softmax
// (|S|<<1: exact softmax, no overflow), exp2 domain (log2e folded into q).
// Q staged to qps, frags hoisted to regs, then qps reused as P buffer
// (rows are wave-private).
// ---------------------------------------------------------------------------
__global__ __launch_bounds__(256, 3) void attn_kernel(
    const short* __restrict__ qg, const short* __restrict__ kg,
    const short* __restrict__ vg, short* __restrict__ at)
{
    __shared__ short qps[128 * 64];      // Q then P, [tt][c|ss] swizzled
    __shared__ short kt[2][64 * 64];     // [ss][c] swizzled, dbuf
    __shared__ short vs[2][64 * 64];     // [c][ss] swizzled, dbuf

    const int tid = threadIdx.x;
    const int wv = tid >> 6, lane = tid & 63;
    const int l16 = lane & 15, quad = lane >> 4;
    const int xr = l16 & 7;
    const int t0 = blockIdx.x * 128;
    const int bh = blockIdx.y;
    const int b = bh >> 3, hd = bh & 7;
    const short* qh = qg + (size_t)bh * NT * CH;
    const short* kh = kg + (size_t)bh * NT * CH;
    const short* vh = vg + (size_t)bh * CH * NT;

    // stage Q (128 rows, 16 instrs; wave wv covers its own rows [wv*32,+32))
    #pragma unroll
    for (int q = 0; q < 4; ++q) {
        const int F = (wv * 4 + q) * 64 + lane;
        const int row = F >> 3, cc = (F & 7) ^ (row & 7);
        gload_lds16(qh + (size_t)(t0 + row) * CH + cc * 8, &qps[(wv * 4 + q) * 512]);
    }
    // issue K/V tile 0 into buf 0
    #pragma unroll
    for (int q = 0; q < 2; ++q) {
        const int F = (wv * 2 + q) * 64 + lane;
        const int row = F >> 3, cc = (F & 7) ^ (row & 7);
        gload_lds16(kh + (size_t)row * CH + cc * 8, &kt[0][(wv * 2 + q) * 512]);
        gload_lds16(vh + (size_t)row * NT + cc * 8, &vs[0][(wv * 2 + q) * 512]);
    }
    __syncthreads();   // drains vmcnt: Q + tile0 resident

    // hoist Q frags (loop-invariant): bq[strip][ks]
    short8 bq[2][2];
    #pragma unroll
    for (int st = 0; st < 2; ++st) {
        const int row = wv * 32 + st * 16 + l16;
        #pragma unroll
        for (int ks = 0; ks < 2; ++ks) {
            const int c = (quad | (ks << 2)) ^ xr;
            bq[st][ks] = *(const short8*)&qps[row * 64 + c * 8];
        }
    }

    floatx4 Oa[2][4];
    #pragma unroll
    for (int st = 0; st < 2; ++st)
        #pragma unroll
        for (int nt = 0; nt < 4; ++nt) Oa[st][nt] = (floatx4){0.f, 0.f, 0.f, 0.f};
    float l_run[2] = {0.f, 0.f};

    for (int it = 0; it < NT / 64; ++it) {
        __syncthreads();   // cur tile data ready; prev tile reads done
        if (it + 1 < NT / 64) {
            const int s0n = (it + 1) * 64;
            short* kb = kt[(it + 1) & 1];
            short* vb = vs[(it + 1) & 1];
            #pragma unroll
            for (int q = 0; q < 2; ++q) {
                const int F = (wv * 2 + q) * 64 + lane;
                const int row = F >> 3, cc = (F & 7) ^ (row & 7);
                gload_lds16(kh + (size_t)(s0n + row) * CH + cc * 8, kb + (wv * 2 + q) * 512);
                gload_lds16(vh + (size_t)row * NT + s0n + cc * 8, vb + (wv * 2 + q) * 512);
            }
        }
        const short* kc = kt[it & 1];
        const short* vc = vs[it & 1];

        // ---- S: D[ss][tt], both strips share each K frag ----
        floatx4 sa0[4], sa1[4];
        #pragma unroll
        for (int nt = 0; nt < 4; ++nt) {
            sa0[nt] = (floatx4){0.f, 0.f, 0.f, 0.f};
            sa1[nt] = (floatx4){0.f, 0.f, 0.f, 0.f};
        }
        #pragma unroll
        for (int ks = 0; ks < 2; ++ks) {
            const int c = (quad | (ks << 2)) ^ xr;
            #pragma unroll
            for (int nt = 0; nt < 4; ++nt) {
                short8 ak = *(const short8*)&kc[(nt * 16 + l16) * 64 + c * 8];
                sa0[nt] = __builtin_amdgcn_mfma_f32_16x16x32_bf16(ak, bq[0][ks], sa0[nt], 0, 0, 0);
                sa1[nt] = __builtin_amdgcn_mfma_f32_16x16x32_bf16(ak, bq[1][ks], sa1[nt], 0, 0, 0);
            }
        }

        // ---- softmax (no max; exp2 domain), lane owns col tt ----
        float rs0 = 0.f, rs1 = 0.f;
        #pragma unroll
        for (int nt = 0; nt < 4; ++nt) {
            #pragma unroll
            for (int r = 0; r < 4; ++r) {
                const float p0 = exp2f(sa0[nt][r]);
                const float p1 = exp2f(sa1[nt][r]);
                sa0[nt][r] = p0; rs0 += p0;
                sa1[nt][r] = p1; rs1 += p1;
            }
        }
        rs0 += __shfl_xor(rs0, 16, 64); rs0 += __shfl_xor(rs0, 32, 64);
        rs1 += __shfl_xor(rs1, 16, 64); rs1 += __shfl_xor(rs1, 32, 64);
        l_run[0] += rs0;
        l_run[1] += rs1;

        // ---- write P (bf16, swizzled) to wave-private qps rows ----
        #pragma unroll
        for (int st = 0; st < 2; ++st) {
            const int row = wv * 32 + st * 16 + l16;
            #pragma unroll
            for (int nt = 0; nt < 4; ++nt) {
                const floatx4 sv = st ? sa1[nt] : sa0[nt];
                short4v s;
                s.x = rne_bf16(sv[0]); s.y = rne_bf16(sv[1]);
                s.z = rne_bf16(sv[2]); s.w = rne_bf16(sv[3]);
                const int cw = (2 * nt + (quad >> 1)) ^ xr;
                *(short4v*)&qps[row * 64 + cw * 8 + (quad & 1) * 4] = s;
            }
        }
        // no barrier: rows wave-private, DS pipe in-order per wave

        // ---- read P frags ----
        short8 bp[2][2];
        #pragma unroll
        for (int st = 0; st < 2; ++st) {
            const int row = wv * 32 + st * 16 + l16;
            #pragma unroll
            for (int ks = 0; ks < 2; ++ks) {
                const int c = (quad | (ks << 2)) ^ xr;
                bp[st][ks] = *(const short8*)&qps[row * 64 + c * 8];
            }
        }

        // ---- PV: D[c][tt], both strips share each V frag ----
        #pragma unroll
        for (int ks = 0; ks < 2; ++ks) {
            const int c = (quad | (ks << 2)) ^ xr;
            #pragma unroll
            for (int nt = 0; nt < 4; ++nt) {
                short8 av = *(const short8*)&vc[(nt * 16 + l16) * 64 + c * 8];
                Oa[0][nt] = __builtin_amdgcn_mfma_f32_16x16x32_bf16(av, bp[0][ks], Oa[0][nt], 0, 0, 0);
                Oa[1][nt] = __builtin_amdgcn_mfma_f32_16x16x32_bf16(av, bp[1][ks], Oa[1][nt], 0, 0, 0);
            }
        }
    }

    // epilogue: attn_t[b][t][hd*64+c]
    #pragma unroll
    for (int st = 0; st < 2; ++st) {
        const float rl = 1.f / l_run[st];
        const int t = t0 + wv * 32 + st * 16 + l16;
        short* dst = at + ((size_t)b * NT + t) * NC + hd * CH;
        #pragma unroll
        for (int nt = 0; nt < 4; ++nt) {
            short4v s;
            s.x = rne_bf16(Oa[st][nt][0] * rl);
            s.y = rne_bf16(Oa[st][nt][1] * rl);
            s.z = rne_bf16(Oa[st][nt][2] * rl);
            s.w = rne_bf16(Oa[st][nt][3] * rl);
            *(short4v*)&dst[nt * 16 + quad * 4] = s;
        }
    }
}

// ---------------------------------------------------------------------------
// Proj GEMM + bias + residual
// ---------------------------------------------------------------------------
__global__ __launch_bounds__(256) void proj_gemm_kernel(
    const short* __restrict__ wb, const short* __restrict__ at,
    const float* __restrict__ bias, const float* __restrict__ xres,
    float* __restrict__ out)
{
    __shared__ short As[128 * BK];
    __shared__ short Bs[128 * BK];
    const int tid = threadIdx.x;
    const int wv = tid >> 6, lane = tid & 63;
    const int l16 = lane & 15, quad = lane >> 4;
    const int n0 = blockIdx.x * 128;
    const int m0 = blockIdx.y * 128;
    const int wm = wv & 1, wn = wv >> 1;

    floatx4 acc[4][4];
    #pragma unroll
    for (int i = 0; i < 4; ++i)
        #pragma unroll
        for (int j = 0; j < 4; ++j) acc[i][j] = (floatx4){0.f, 0.f, 0.f, 0.f};

    const short* gsrc = (wv < 2) ? wb : at;
    const int rbase = (wv & 1) * 64;
    const int tile0 = (wv < 2) ? m0 : n0;
    short* lbuf = (wv < 2) ? As : Bs;
    const int lrow = lane >> 2;
    const int lcol = (lane & 3) * 8;

    for (int k0 = 0; k0 < 512; k0 += BK) {
        __syncthreads();
        #pragma unroll
        for (int ch = 0; ch < 4; ++ch) {
            const int row = rbase + ch * 16 + lrow;
            gload_lds16(gsrc + (size_t)(tile0 + row) * 512 + k0 + lcol,
                        lbuf + (rbase + ch * 16) * BK);
        }
        __syncthreads();

        short8 af[4], bfr[4];
        #pragma unroll
        for (int i = 0; i < 4; ++i) {
            af[i]  = *(const short8*)&As[(wm * 64 + i * 16 + l16) * BK + quad * 8];
            bfr[i] = *(const short8*)&Bs[(wn * 64 + i * 16 + l16) * BK + quad * 8];
        }
        #pragma unroll
        for (int i = 0; i < 4; ++i)
            #pragma unroll
            for (int j = 0; j < 4; ++j)
                acc[i][j] = __builtin_amdgcn_mfma_f32_16x16x32_bf16(
                    af[i], bfr[j], acc[i][j], 0, 0, 0);
    }

    #pragma unroll
    for (int i = 0; i < 4; ++i) {
        const int o16 = m0 + wm * 64 + i * 16;
        const float4 b4 = *(const float4*)&bias[o16 + quad * 4];
        #pragma unroll
        for (int j = 0; j < 4; ++j) {
            const int tg = n0 + wn * 64 + j * 16 + l16;
            const int b = tg >> 11, t = tg & 2047;
            const size_t base = ((size_t)b * NC + o16 + quad * 4) * NT + t;
            floatx4 v = acc[i][j];
            out[base]          = v[0] + b4.x + xres[base];
            out[base + NT]     = v[1] + b4.y + xres[base + NT];
            out[base + 2 * NT] = v[2] + b4.z + xres[base + 2 * NT];
            out[base + 3 * NT] = v[3] + b4.w + xres[base + 3 * NT];
        }
    }
}

// ---------------------------------------------------------------------------
extern "C" void kernel_launch(void* const* d_in, const int* in_sizes, int n_in,
                              void* d_out, int out_size, void* d_ws, size_t ws_size,
                              hipStream_t stream)
{
    const float* x      = (const float*)d_in[0];
    const float* gn_w   = (const float*)d_in[1];
    const float* gn_b   = (const float*)d_in[2];
    const float* qkv_w  = (const float*)d_in[3];
    const float* qkv_b  = (const float*)d_in[4];
    const float* proj_w = (const float*)d_in[5];
    const float* proj_b = (const float*)d_in[6];
    float* out = (float*)d_out;

    short* ht  = (short*)d_ws;            // [8*2048][512]
    short* q_t = ht  + 8388608;           // [64][2048][64]
    short* k_t = q_t + 8388608;
    short* vv  = k_t + 8388608;           // [64][64][2048]
    short* at  = vv  + 8388608;           // [8*2048][512]
    short* qwb = at  + 8388608;           // [1536][512]
    short* pwb = qwb + 786432;            // [512][512]
    float* stats = (float*)(pwb + 262144);

    castw_kernel<<<768, 256, 0, stream>>>(qkv_w, qwb, 1536 * 512 / 4);
    castw_kernel<<<256, 256, 0, stream>>>(proj_w, pwb, 512 * 512 / 4);
    gn_stats_kernel<<<NB * NG, 256, 0, stream>>>(x, stats);
    gn_apply_kernel<<<dim3(NT / 64, NB), 256, 0, stream>>>(x, gn_w, gn_b, stats, ht);
    qkv_gemm_kernel<<<dim3(128, 12), 256, 0, stream>>>(qwb, ht, qkv_b, q_t, k_t, vv);
    attn_kernel<<<dim3(NT / 128, NB * NH), 256, 0, stream>>>(q_t, k_t, vv, at);
    proj_gemm_kernel<<<dim3(128, 4), 256, 0, stream>>>(pwb, at, proj_b, x, out);
}

// Round 6
// 311.130 us; speedup vs baseline: 5.2286x; 1.0101x over previous
//
#include <hip/hip_runtime.h>
#include <hip/hip_bf16.h>
#include <math.h>

// Problem constants: B=8, C=512, T=2048, G=32, HEADS=8, CH=64
#define NB 8
#define NC 512
#define NT 2048
#define NG 32
#define NH 8
#define CH 64

typedef __attribute__((ext_vector_type(8))) short short8;   // 8 bf16
typedef __attribute__((ext_vector_type(4))) short short4v;  // 4 bf16 (8B)
typedef __attribute__((ext_vector_type(4))) float floatx4;  // MFMA C/D

static __device__ __forceinline__ short f2bf(float f) {
    __hip_bfloat16 h = __float2bfloat16(f);
    return *reinterpret_cast<short*>(&h);
}

// RNE round of one f32 to bf16 bits (finite values)
static __device__ __forceinline__ unsigned rne_u(float f) {
    unsigned u = __builtin_bit_cast(unsigned, f);
    return u + 0x7FFFu + ((u >> 16) & 1u);
}

// pack 2 f32 -> 2 bf16 in an int (a = low short), RNE
static __device__ __forceinline__ int pk2bf(float a, float b) {
    return (int)((rne_u(a) >> 16) | (rne_u(b) & 0xFFFF0000u));
}

static __device__ __forceinline__ void gload_lds16(const short* g, short* l) {
    __builtin_amdgcn_global_load_lds(
        (const __attribute__((address_space(1))) void*)g,
        (__attribute__((address_space(3))) void*)l, 16, 0, 0);
}

// ---------------------------------------------------------------------------
// fp32 -> bf16 cast (weights)
// ---------------------------------------------------------------------------
__global__ __launch_bounds__(256) void castw_kernel(
    const float* __restrict__ w, short* __restrict__ o, int n4)
{
    const int i = blockIdx.x * 256 + threadIdx.x;
    if (i < n4) {
        float4 v = ((const float4*)w)[i];
        short4v s;
        s.x = f2bf(v.x); s.y = f2bf(v.y); s.z = f2bf(v.z); s.w = f2bf(v.w);
        *(short4v*)&o[i * 4] = s;
    }
}

// ---------------------------------------------------------------------------
// GroupNorm stats
// ---------------------------------------------------------------------------
__global__ __launch_bounds__(256) void gn_stats_kernel(
    const float* __restrict__ x, float* __restrict__ stats)
{
    __shared__ float red[16];
    const int tid = threadIdx.x;
    const int grp = blockIdx.x;
    const float4* xp = (const float4*)(x + (size_t)grp * 16 * NT);

    float s = 0.f, ss = 0.f;
    for (int i = tid; i < 8192; i += 256) {
        float4 v = xp[i];
        s  += v.x + v.y + v.z + v.w;
        ss += v.x*v.x + v.y*v.y + v.z*v.z + v.w*v.w;
    }
    #pragma unroll
    for (int o = 32; o > 0; o >>= 1) {
        s  += __shfl_down(s,  o, 64);
        ss += __shfl_down(ss, o, 64);
    }
    const int lane = tid & 63, wid = tid >> 6;
    if (lane == 0) { red[wid] = s; red[8 + wid] = ss; }
    __syncthreads();
    if (tid == 0) {
        const float inv = 1.f / 32768.f;
        const float mean = (red[0] + red[1] + red[2] + red[3]) * inv;
        const float var  = (red[8] + red[9] + red[10] + red[11]) * inv - mean * mean;
        stats[grp * 2]     = mean;
        stats[grp * 2 + 1] = rsqrtf(var + 1e-5f);
    }
}

// ---------------------------------------------------------------------------
// GroupNorm apply + transpose + bf16: h_t[b][t][c]
// ---------------------------------------------------------------------------
__global__ __launch_bounds__(256) void gn_apply_kernel(
    const float* __restrict__ x, const float* __restrict__ gw,
    const float* __restrict__ gb, const float* __restrict__ stats,
    short* __restrict__ ht)
{
    __shared__ float wc_s[NC], bc_s[NC];
    const int tid = threadIdx.x;
    const int b = blockIdx.y;
    const int t0 = blockIdx.x * 64;

    for (int c = tid; c < NC; c += 256) {
        const int g = c >> 4;
        const float mean = stats[(b * NG + g) * 2];
        const float rstd = stats[(b * NG + g) * 2 + 1];
        const float wc = gw[c] * rstd;
        wc_s[c] = wc;
        bc_s[c] = gb[c] - mean * wc;
    }
    __syncthreads();

    const int t  = t0 + (tid >> 2);
    const int lc = tid & 3;
    const float* xb = x + (size_t)b * NC * NT + t;
    short* out = ht + ((size_t)b * NT + t) * NC;

    for (int k = 0; k < 16; ++k) {
        const int c0 = lc * 8 + k * 32;
        short8 v;
        #pragma unroll
        for (int j = 0; j < 8; ++j) {
            const int c = c0 + j;
            v[j] = f2bf(xb[(size_t)c * NT] * wc_s[c] + bc_s[c]);
        }
        *(short8*)&out[c0] = v;
    }
}

// ---------------------------------------------------------------------------
// QKV GEMM (m97-style). Epilogue: q gets scale*log2e (exp2 softmax),
// k gets scale; v natural layout.
// ---------------------------------------------------------------------------
#define BK 32
__global__ __launch_bounds__(256) void qkv_gemm_kernel(
    const short* __restrict__ wb, const short* __restrict__ ht,
    const float* __restrict__ bias,
    short* __restrict__ q_t, short* __restrict__ k_t, short* __restrict__ vv)
{
    __shared__ short As[128 * BK];
    __shared__ short Bs[128 * BK];
    const int tid = threadIdx.x;
    const int wv = tid >> 6, lane = tid & 63;
    const int l16 = lane & 15, quad = lane >> 4;
    const int n0 = blockIdx.x * 128;
    const int m0 = blockIdx.y * 128;
    const int wm = wv & 1, wn = wv >> 1;

    floatx4 acc[4][4];
    #pragma unroll
    for (int i = 0; i < 4; ++i)
        #pragma unroll
        for (int j = 0; j < 4; ++j) acc[i][j] = (floatx4){0.f, 0.f, 0.f, 0.f};

    const short* gsrc = (wv < 2) ? wb : ht;
    const int rbase = (wv & 1) * 64;
    const int tile0 = (wv < 2) ? m0 : n0;
    short* lbuf = (wv < 2) ? As : Bs;
    const int lrow = lane >> 2;
    const int lcol = (lane & 3) * 8;

    for (int k0 = 0; k0 < 512; k0 += BK) {
        __syncthreads();
        #pragma unroll
        for (int ch = 0; ch < 4; ++ch) {
            const int row = rbase + ch * 16 + lrow;
            gload_lds16(gsrc + (size_t)(tile0 + row) * 512 + k0 + lcol,
                        lbuf + (rbase + ch * 16) * BK);
        }
        __syncthreads();

        short8 af[4], bfr[4];
        #pragma unroll
        for (int i = 0; i < 4; ++i) {
            af[i]  = *(const short8*)&As[(wm * 64 + i * 16 + l16) * BK + quad * 8];
            bfr[i] = *(const short8*)&Bs[(wn * 64 + i * 16 + l16) * BK + quad * 8];
        }
        #pragma unroll
        for (int i = 0; i < 4; ++i)
            #pragma unroll
            for (int j = 0; j < 4; ++j)
                acc[i][j] = __builtin_amdgcn_mfma_f32_16x16x32_bf16(
                    af[i], bfr[j], acc[i][j], 0, 0, 0);
    }

    const float kscale = 0.35355339059327373f;              // 64^-0.25
    const float qscale = 0.35355339059327373f * 1.4426950408889634f; // * log2(e)
    #pragma unroll
    for (int i = 0; i < 4; ++i) {
        const int o16 = m0 + wm * 64 + i * 16;
        const int sel = o16 >> 9;
        const int hh  = (o16 >> 6) & 7;
        const int c16 = o16 & 63;
        const float4 b4 = *(const float4*)&bias[o16 + quad * 4];
        const float sc = (sel == 0) ? qscale : kscale;
        #pragma unroll
        for (int j = 0; j < 4; ++j) {
            const int tg = n0 + wn * 64 + j * 16 + l16;
            const int b = tg >> 11, t = tg & 2047;
            floatx4 v = acc[i][j];
            v[0] += b4.x; v[1] += b4.y; v[2] += b4.z; v[3] += b4.w;
            if (sel < 2) {
                short4v s;
                s.x = f2bf(v[0] * sc); s.y = f2bf(v[1] * sc);
                s.z = f2bf(v[2] * sc); s.w = f2bf(v[3] * sc);
                short* dst = (sel == 0 ? q_t : k_t) +
                    (((size_t)(b * NH + hh) * NT + t) * CH + c16 + quad * 4);
                *(short4v*)dst = s;
            } else {
                short* dst = vv + ((size_t)(b * NH + hh) * CH + c16 + quad * 4) * NT + t;
                #pragma unroll
                for (int r = 0; r < 4; ++r) dst[(size_t)r * NT] = f2bf(v[r]);
            }
        }
    }
}

// ---------------------------------------------------------------------------
// Flash attention v5. Block = 256 tt x 1 bh, 4 waves; wave owns 64 tt
// (4 tiles of 16). K/V frags shared across 4 tt-tiles -> LDS bytes/S-element
// ~9 (was 14). XOR-swizzled pad-free LDS; global_load_lds staging; K/V
// double-buffered, 1 barrier/tile. No-max exp2 softmax. Q staged to qps,
// frags hoisted (8x short8), qps reused as wave-private P buffer.
// ---------------------------------------------------------------------------
__global__ __launch_bounds__(256, 2) void attn_kernel(
    const short* __restrict__ qg, const short* __restrict__ kg,
    const short* __restrict__ vg, short* __restrict__ at)
{
    __shared__ short qps[256 * 64];      // 32 KB: Q then P (wave-private rows)
    __shared__ short kt[2][64 * 64];     // 16 KB: [ss][c] swizzled, dbuf
    __shared__ short vs[2][64 * 64];     // 16 KB: [c][ss] swizzled, dbuf

    const int tid = threadIdx.x;
    const int wv = tid >> 6, lane = tid & 63;
    const int l16 = lane & 15, quad = lane >> 4;
    const int xr = l16 & 7;
    const int t0 = blockIdx.x * 256;
    const int bh = blockIdx.y;
    const int b = bh >> 3, hd = bh & 7;
    const short* qh = qg + (size_t)bh * NT * CH;
    const short* kh = kg + (size_t)bh * NT * CH;
    const short* vh = vg + (size_t)bh * CH * NT;

    // stage Q: 256 rows; wave wv stages its own rows [wv*64, +64) (8 instrs)
    #pragma unroll
    for (int q = 0; q < 8; ++q) {
        const int F = (wv * 8 + q) * 64 + lane;
        const int row = F >> 3, cc = (F & 7) ^ (row & 7);
        gload_lds16(qh + (size_t)(t0 + row) * CH + cc * 8, &qps[(wv * 8 + q) * 512]);
    }
    // K/V tile 0 into buf 0
    #pragma unroll
    for (int q = 0; q < 2; ++q) {
        const int F = (wv * 2 + q) * 64 + lane;
        const int row = F >> 3, cc = (F & 7) ^ (row & 7);
        gload_lds16(kh + (size_t)row * CH + cc * 8, &kt[0][(wv * 2 + q) * 512]);
        gload_lds16(vh + (size_t)row * NT + cc * 8, &vs[0][(wv * 2 + q) * 512]);
    }
    __syncthreads();   // drains vmcnt: Q + tile0 resident

    // hoist Q frags: bq[qt][ks], tt row = wv*64 + qt*16 + l16
    short8 bq[4][2];
    #pragma unroll
    for (int qt = 0; qt < 4; ++qt) {
        const int row = wv * 64 + qt * 16 + l16;
        #pragma unroll
        for (int ks = 0; ks < 2; ++ks) {
            const int c = (quad | (ks << 2)) ^ xr;
            bq[qt][ks] = *(const short8*)&qps[row * 64 + c * 8];
        }
    }

    floatx4 Oa[4][4];   // [ct][qt]: D[c][tt]
    #pragma unroll
    for (int ct = 0; ct < 4; ++ct)
        #pragma unroll
        for (int qt = 0; qt < 4; ++qt) Oa[ct][qt] = (floatx4){0.f, 0.f, 0.f, 0.f};
    float l_run[4] = {0.f, 0.f, 0.f, 0.f};

    for (int it = 0; it < NT / 64; ++it) {
        __syncthreads();   // cur tile ready; prev tile frag reads done
        if (it + 1 < NT / 64) {
            const int s0n = (it + 1) * 64;
            short* kb = kt[(it + 1) & 1];
            short* vb = vs[(it + 1) & 1];
            #pragma unroll
            for (int q = 0; q < 2; ++q) {
                const int F = (wv * 2 + q) * 64 + lane;
                const int row = F >> 3, cc = (F & 7) ^ (row & 7);
                gload_lds16(kh + (size_t)(s0n + row) * CH + cc * 8, kb + (wv * 2 + q) * 512);
                gload_lds16(vh + (size_t)row * NT + s0n + cc * 8, vb + (wv * 2 + q) * 512);
            }
        }
        const short* kc = kt[it & 1];
        const short* vc = vs[it & 1];

        // ---- S: D[ss][tt]; each K frag feeds 4 tt-tiles ----
        floatx4 sacc[4][4];   // [nt=ss-tile][qt=tt-tile]
        #pragma unroll
        for (int nt = 0; nt < 4; ++nt)
            #pragma unroll
            for (int qt = 0; qt < 4; ++qt) sacc[nt][qt] = (floatx4){0.f, 0.f, 0.f, 0.f};
        #pragma unroll
        for (int ks = 0; ks < 2; ++ks) {
            const int c = (quad | (ks << 2)) ^ xr;
            #pragma unroll
            for (int nt = 0; nt < 4; ++nt) {
                short8 ak = *(const short8*)&kc[(nt * 16 + l16) * 64 + c * 8];
                #pragma unroll
                for (int qt = 0; qt < 4; ++qt)
                    sacc[nt][qt] = __builtin_amdgcn_mfma_f32_16x16x32_bf16(
                        ak, bq[qt][ks], sacc[nt][qt], 0, 0, 0);
            }
        }

        // ---- softmax (no max; exp2 domain); lane owns col tt per qt ----
        #pragma unroll
        for (int qt = 0; qt < 4; ++qt) {
            float rs = 0.f;
            #pragma unroll
            for (int nt = 0; nt < 4; ++nt) {
                #pragma unroll
                for (int r = 0; r < 4; ++r) {
                    const float p = exp2f(sacc[nt][qt][r]);
                    sacc[nt][qt][r] = p;
                    rs += p;
                }
            }
            rs += __shfl_xor(rs, 16, 64);
            rs += __shfl_xor(rs, 32, 64);
            l_run[qt] += rs;
        }

        // ---- write P (bf16, swizzled) into wave-private qps rows ----
        #pragma unroll
        for (int qt = 0; qt < 4; ++qt) {
            const int row = wv * 64 + qt * 16 + l16;
            #pragma unroll
            for (int nt = 0; nt < 4; ++nt) {
                const int cw = (2 * nt + (quad >> 1)) ^ xr;
                int2 pv;
                pv.x = pk2bf(sacc[nt][qt][0], sacc[nt][qt][1]);
                pv.y = pk2bf(sacc[nt][qt][2], sacc[nt][qt][3]);
                *(int2*)&qps[row * 64 + cw * 8 + (quad & 1) * 4] = pv;
            }
        }
        // no barrier: rows wave-private; DS pipe in-order per wave

        // ---- PV: D[c][tt]; each V frag feeds 4 tt-tiles ----
        #pragma unroll
        for (int ks = 0; ks < 2; ++ks) {
            const int c = (quad | (ks << 2)) ^ xr;
            short8 bp[4];
            #pragma unroll
            for (int qt = 0; qt < 4; ++qt)
                bp[qt] = *(const short8*)&qps[(wv * 64 + qt * 16 + l16) * 64 + c * 8];
            #pragma unroll
            for (int ct = 0; ct < 4; ++ct) {
                short8 av = *(const short8*)&vc[(ct * 16 + l16) * 64 + c * 8];
                #pragma unroll
                for (int qt = 0; qt < 4; ++qt)
                    Oa[ct][qt] = __builtin_amdgcn_mfma_f32_16x16x32_bf16(
                        av, bp[qt], Oa[ct][qt], 0, 0, 0);
            }
        }
    }

    // epilogue: attn_t[b][t][hd*64+c]; lane col tt=l16, rows c=16ct+quad*4+r
    #pragma unroll
    for (int qt = 0; qt < 4; ++qt) {
        const float rl = 1.f / l_run[qt];
        const int t = t0 + wv * 64 + qt * 16 + l16;
        short* dst = at + ((size_t)b * NT + t) * NC + hd * CH;
        #pragma unroll
        for (int ct = 0; ct < 4; ++ct) {
            int2 s;
            s.x = pk2bf(Oa[ct][qt][0] * rl, Oa[ct][qt][1] * rl);
            s.y = pk2bf(Oa[ct][qt][2] * rl, Oa[ct][qt][3] * rl);
            *(int2*)&dst[ct * 16 + quad * 4] = s;
        }
    }
}

// ---------------------------------------------------------------------------
// Proj GEMM + bias + residual
// ---------------------------------------------------------------------------
__global__ __launch_bounds__(256) void proj_gemm_kernel(
    const short* __restrict__ wb, const short* __restrict__ at,
    const float* __restrict__ bias, const float* __restrict__ xres,
    float* __restrict__ out)
{
    __shared__ short As[128 * BK];
    __shared__ short Bs[128 * BK];
    const int tid = threadIdx.x;
    const int wv = tid >> 6, lane = tid & 63;
    const int l16 = lane & 15, quad = lane >> 4;
    const int n0 = blockIdx.x * 128;
    const int m0 = blockIdx.y * 128;
    const int wm = wv & 1, wn = wv >> 1;

    floatx4 acc[4][4];
    #pragma unroll
    for (int i = 0; i < 4; ++i)
        #pragma unroll
        for (int j = 0; j < 4; ++j) acc[i][j] = (floatx4){0.f, 0.f, 0.f, 0.f};

    const short* gsrc = (wv < 2) ? wb : at;
    const int rbase = (wv & 1) * 64;
    const int tile0 = (wv < 2) ? m0 : n0;
    short* lbuf = (wv < 2) ? As : Bs;
    const int lrow = lane >> 2;
    const int lcol = (lane & 3) * 8;

    for (int k0 = 0; k0 < 512; k0 += BK) {
        __syncthreads();
        #pragma unroll
        for (int ch = 0; ch < 4; ++ch) {
            const int row = rbase + ch * 16 + lrow;
            gload_lds16(gsrc + (size_t)(tile0 + row) * 512 + k0 + lcol,
                        lbuf + (rbase + ch * 16) * BK);
        }
        __syncthreads();

        short8 af[4], bfr[4];
        #pragma unroll
        for (int i = 0; i < 4; ++i) {
            af[i]  = *(const short8*)&As[(wm * 64 + i * 16 + l16) * BK + quad * 8];
            bfr[i] = *(const short8*)&Bs[(wn * 64 + i * 16 + l16) * BK + quad * 8];
        }
        #pragma unroll
        for (int i = 0; i < 4; ++i)
            #pragma unroll
            for (int j = 0; j < 4; ++j)
                acc[i][j] = __builtin_amdgcn_mfma_f32_16x16x32_bf16(
                    af[i], bfr[j], acc[i][j], 0, 0, 0);
    }

    #pragma unroll
    for (int i = 0; i < 4; ++i) {
        const int o16 = m0 + wm * 64 + i * 16;
        const float4 b4 = *(const float4*)&bias[o16 + quad * 4];
        #pragma unroll
        for (int j = 0; j < 4; ++j) {
            const int tg = n0 + wn * 64 + j * 16 + l16;
            const int b = tg >> 11, t = tg & 2047;
            const size_t base = ((size_t)b * NC + o16 + quad * 4) * NT + t;
            floatx4 v = acc[i][j];
            out[base]          = v[0] + b4.x + xres[base];
            out[base + NT]     = v[1] + b4.y + xres[base + NT];
            out[base + 2 * NT] = v[2] + b4.z + xres[base + 2 * NT];
            out[base + 3 * NT] = v[3] + b4.w + xres[base + 3 * NT];
        }
    }
}

// ---------------------------------------------------------------------------
extern "C" void kernel_launch(void* const* d_in, const int* in_sizes, int n_in,
                              void* d_out, int out_size, void* d_ws, size_t ws_size,
                              hipStream_t stream)
{
    const float* x      = (const float*)d_in[0];
    const float* gn_w   = (const float*)d_in[1];
    const float* gn_b   = (const float*)d_in[2];
    const float* qkv_w  = (const float*)d_in[3];
    const float* qkv_b  = (const float*)d_in[4];
    const float* proj_w = (const float*)d_in[5];
    const float* proj_b = (const float*)d_in[6];
    float* out = (float*)d_out;

    short* ht  = (short*)d_ws;            // [8*2048][512]
    short* q_t = ht  + 8388608;           // [64][2048][64]
    short* k_t = q_t + 8388608;
    short* vv  = k_t + 8388608;           // [64][64][2048]
    short* at  = vv  + 8388608;           // [8*2048][512]
    short* qwb = at  + 8388608;           // [1536][512]
    short* pwb = qwb + 786432;            // [512][512]
    float* stats = (float*)(pwb + 262144);

    castw_kernel<<<768, 256, 0, stream>>>(qkv_w, qwb, 1536 * 512 / 4);
    castw_kernel<<<256, 256, 0, stream>>>(proj_w, pwb, 512 * 512 / 4);
    gn_stats_kernel<<<NB * NG, 256, 0, stream>>>(x, stats);
    gn_apply_kernel<<<dim3(NT / 64, NB), 256, 0, stream>>>(x, gn_w, gn_b, stats, ht);
    qkv_gemm_kernel<<<dim3(128, 12), 256, 0, stream>>>(qwb, ht, qkv_b, q_t, k_t, vv);
    attn_kernel<<<dim3(NT / 256, NB * NH), 256, 0, stream>>>(q_t, k_t, vv, at);
    proj_gemm_kernel<<<dim3(128, 4), 256, 0, stream>>>(pwb, at, proj_b, x, out);
}

// Round 7
// 266.754 us; speedup vs baseline: 6.0984x; 1.1664x over previous
//
#include <hip/hip_runtime.h>
#include <hip/hip_bf16.h>
#include <math.h>

// Problem constants: B=8, C=512, T=2048, G=32, HEADS=8, CH=64
#define NB 8
#define NC 512
#define NT 2048
#define NG 32
#define NH 8
#define CH 64

typedef __attribute__((ext_vector_type(8))) short short8;   // 8 bf16
typedef __attribute__((ext_vector_type(4))) short short4v;  // 4 bf16 (8B)
typedef __attribute__((ext_vector_type(4))) float floatx4;  // MFMA C/D

static __device__ __forceinline__ short f2bf(float f) {
    __hip_bfloat16 h = __float2bfloat16(f);
    return *reinterpret_cast<short*>(&h);
}

// pack high halves of two f32 (truncation to bf16): 1 v_perm_b32
static __device__ __forceinline__ int pk2bf_trunc(float lo, float hi) {
    return (int)__builtin_amdgcn_perm(__builtin_bit_cast(unsigned, hi),
                                      __builtin_bit_cast(unsigned, lo),
                                      0x07060302u);
}

static __device__ __forceinline__ void gload_lds16(const short* g, short* l) {
    __builtin_amdgcn_global_load_lds(
        (const __attribute__((address_space(1))) void*)g,
        (__attribute__((address_space(3))) void*)l, 16, 0, 0);
}

// ---------------------------------------------------------------------------
// fp32 -> bf16 cast (weights)
// ---------------------------------------------------------------------------
__global__ __launch_bounds__(256) void castw_kernel(
    const float* __restrict__ w, short* __restrict__ o, int n4)
{
    const int i = blockIdx.x * 256 + threadIdx.x;
    if (i < n4) {
        float4 v = ((const float4*)w)[i];
        short4v s;
        s.x = f2bf(v.x); s.y = f2bf(v.y); s.z = f2bf(v.z); s.w = f2bf(v.w);
        *(short4v*)&o[i * 4] = s;
    }
}

// ---------------------------------------------------------------------------
// GroupNorm stats
// ---------------------------------------------------------------------------
__global__ __launch_bounds__(256) void gn_stats_kernel(
    const float* __restrict__ x, float* __restrict__ stats)
{
    __shared__ float red[16];
    const int tid = threadIdx.x;
    const int grp = blockIdx.x;
    const float4* xp = (const float4*)(x + (size_t)grp * 16 * NT);

    float s = 0.f, ss = 0.f;
    for (int i = tid; i < 8192; i += 256) {
        float4 v = xp[i];
        s  += v.x + v.y + v.z + v.w;
        ss += v.x*v.x + v.y*v.y + v.z*v.z + v.w*v.w;
    }
    #pragma unroll
    for (int o = 32; o > 0; o >>= 1) {
        s  += __shfl_down(s,  o, 64);
        ss += __shfl_down(ss, o, 64);
    }
    const int lane = tid & 63, wid = tid >> 6;
    if (lane == 0) { red[wid] = s; red[8 + wid] = ss; }
    __syncthreads();
    if (tid == 0) {
        const float inv = 1.f / 32768.f;
        const float mean = (red[0] + red[1] + red[2] + red[3]) * inv;
        const float var  = (red[8] + red[9] + red[10] + red[11]) * inv - mean * mean;
        stats[grp * 2]     = mean;
        stats[grp * 2 + 1] = rsqrtf(var + 1e-5f);
    }
}

// ---------------------------------------------------------------------------
// GroupNorm apply + transpose + bf16: h_t[b][t][c]
// ---------------------------------------------------------------------------
__global__ __launch_bounds__(256) void gn_apply_kernel(
    const float* __restrict__ x, const float* __restrict__ gw,
    const float* __restrict__ gb, const float* __restrict__ stats,
    short* __restrict__ ht)
{
    __shared__ float wc_s[NC], bc_s[NC];
    const int tid = threadIdx.x;
    const int b = blockIdx.y;
    const int t0 = blockIdx.x * 64;

    for (int c = tid; c < NC; c += 256) {
        const int g = c >> 4;
        const float mean = stats[(b * NG + g) * 2];
        const float rstd = stats[(b * NG + g) * 2 + 1];
        const float wc = gw[c] * rstd;
        wc_s[c] = wc;
        bc_s[c] = gb[c] - mean * wc;
    }
    __syncthreads();

    const int t  = t0 + (tid >> 2);
    const int lc = tid & 3;
    const float* xb = x + (size_t)b * NC * NT + t;
    short* out = ht + ((size_t)b * NT + t) * NC;

    for (int k = 0; k < 16; ++k) {
        const int c0 = lc * 8 + k * 32;
        short8 v;
        #pragma unroll
        for (int j = 0; j < 8; ++j) {
            const int c = c0 + j;
            v[j] = f2bf(xb[(size_t)c * NT] * wc_s[c] + bc_s[c]);
        }
        *(short8*)&out[c0] = v;
    }
}

// ---------------------------------------------------------------------------
// QKV GEMM (m97-style). Epilogue: q gets scale*log2e (exp2 softmax),
// k gets scale; v natural layout.
// ---------------------------------------------------------------------------
#define BK 32
__global__ __launch_bounds__(256) void qkv_gemm_kernel(
    const short* __restrict__ wb, const short* __restrict__ ht,
    const float* __restrict__ bias,
    short* __restrict__ q_t, short* __restrict__ k_t, short* __restrict__ vv)
{
    __shared__ short As[128 * BK];
    __shared__ short Bs[128 * BK];
    const int tid = threadIdx.x;
    const int wv = tid >> 6, lane = tid & 63;
    const int l16 = lane & 15, quad = lane >> 4;
    const int n0 = blockIdx.x * 128;
    const int m0 = blockIdx.y * 128;
    const int wm = wv & 1, wn = wv >> 1;

    floatx4 acc[4][4];
    #pragma unroll
    for (int i = 0; i < 4; ++i)
        #pragma unroll
        for (int j = 0; j < 4; ++j) acc[i][j] = (floatx4){0.f, 0.f, 0.f, 0.f};

    const short* gsrc = (wv < 2) ? wb : ht;
    const int rbase = (wv & 1) * 64;
    const int tile0 = (wv < 2) ? m0 : n0;
    short* lbuf = (wv < 2) ? As : Bs;
    const int lrow = lane >> 2;
    const int lcol = (lane & 3) * 8;

    for (int k0 = 0; k0 < 512; k0 += BK) {
        __syncthreads();
        #pragma unroll
        for (int ch = 0; ch < 4; ++ch) {
            const int row = rbase + ch * 16 + lrow;
            gload_lds16(gsrc + (size_t)(tile0 + row) * 512 + k0 + lcol,
                        lbuf + (rbase + ch * 16) * BK);
        }
        __syncthreads();

        short8 af[4], bfr[4];
        #pragma unroll
        for (int i = 0; i < 4; ++i) {
            af[i]  = *(const short8*)&As[(wm * 64 + i * 16 + l16) * BK + quad * 8];
            bfr[i] = *(const short8*)&Bs[(wn * 64 + i * 16 + l16) * BK + quad * 8];
        }
        #pragma unroll
        for (int i = 0; i < 4; ++i)
            #pragma unroll
            for (int j = 0; j < 4; ++j)
                acc[i][j] = __builtin_amdgcn_mfma_f32_16x16x32_bf16(
                    af[i], bfr[j], acc[i][j], 0, 0, 0);
    }

    const float kscale = 0.35355339059327373f;              // 64^-0.25
    const float qscale = 0.35355339059327373f * 1.4426950408889634f; // * log2(e)
    #pragma unroll
    for (int i = 0; i < 4; ++i) {
        const int o16 = m0 + wm * 64 + i * 16;
        const int sel = o16 >> 9;
        const int hh  = (o16 >> 6) & 7;
        const int c16 = o16 & 63;
        const float4 b4 = *(const float4*)&bias[o16 + quad * 4];
        const float sc = (sel == 0) ? qscale : kscale;
        #pragma unroll
        for (int j = 0; j < 4; ++j) {
            const int tg = n0 + wn * 64 + j * 16 + l16;
            const int b = tg >> 11, t = tg & 2047;
            floatx4 v = acc[i][j];
            v[0] += b4.x; v[1] += b4.y; v[2] += b4.z; v[3] += b4.w;
            if (sel < 2) {
                short4v s;
                s.x = f2bf(v[0] * sc); s.y = f2bf(v[1] * sc);
                s.z = f2bf(v[2] * sc); s.w = f2bf(v[3] * sc);
                short* dst = (sel == 0 ? q_t : k_t) +
                    (((size_t)(b * NH + hh) * NT + t) * CH + c16 + quad * 4);
                *(short4v*)dst = s;
            } else {
                short* dst = vv + ((size_t)(b * NH + hh) * CH + c16 + quad * 4) * NT + t;
                #pragma unroll
                for (int r = 0; r < 4; ++r) dst[(size_t)r * NT] = f2bf(v[r]);
            }
        }
    }
}

// ---------------------------------------------------------------------------
// Flash attention v6 = v5 structure + VALU diet:
//  - per-lane l partials only (cross-lane reduction deferred to epilogue)
//  - tree-summed exp accumulation (depth 4, no serial chain)
//  - P/O packed via v_perm_b32 truncation (1 inst / 2 values)
//  - bare v_exp_f32 via __builtin_amdgcn_exp2f
// Block = 256 tt x 1 bh, 4 waves; wave owns 64 tt. XOR-swizzled LDS,
// global_load_lds staging, K/V double-buffered, 1 barrier/tile.
// ---------------------------------------------------------------------------
__global__ __launch_bounds__(256, 2) void attn_kernel(
    const short* __restrict__ qg, const short* __restrict__ kg,
    const short* __restrict__ vg, short* __restrict__ at)
{
    __shared__ short qps[256 * 64];      // 32 KB: Q then P (wave-private rows)
    __shared__ short kt[2][64 * 64];     // 16 KB: [ss][c] swizzled, dbuf
    __shared__ short vs[2][64 * 64];     // 16 KB: [c][ss] swizzled, dbuf

    const int tid = threadIdx.x;
    const int wv = tid >> 6, lane = tid & 63;
    const int l16 = lane & 15, quad = lane >> 4;
    const int xr = l16 & 7;
    const int t0 = blockIdx.x * 256;
    const int bh = blockIdx.y;
    const int b = bh >> 3, hd = bh & 7;
    const short* qh = qg + (size_t)bh * NT * CH;
    const short* kh = kg + (size_t)bh * NT * CH;
    const short* vh = vg + (size_t)bh * CH * NT;

    // stage Q: 256 rows; wave wv stages its own rows [wv*64, +64) (8 instrs)
    #pragma unroll
    for (int q = 0; q < 8; ++q) {
        const int F = (wv * 8 + q) * 64 + lane;
        const int row = F >> 3, cc = (F & 7) ^ (row & 7);
        gload_lds16(qh + (size_t)(t0 + row) * CH + cc * 8, &qps[(wv * 8 + q) * 512]);
    }
    // K/V tile 0 into buf 0
    #pragma unroll
    for (int q = 0; q < 2; ++q) {
        const int F = (wv * 2 + q) * 64 + lane;
        const int row = F >> 3, cc = (F & 7) ^ (row & 7);
        gload_lds16(kh + (size_t)row * CH + cc * 8, &kt[0][(wv * 2 + q) * 512]);
        gload_lds16(vh + (size_t)row * NT + cc * 8, &vs[0][(wv * 2 + q) * 512]);
    }
    __syncthreads();   // drains vmcnt: Q + tile0 resident

    // hoist Q frags: bq[qt][ks], tt row = wv*64 + qt*16 + l16
    short8 bq[4][2];
    #pragma unroll
    for (int qt = 0; qt < 4; ++qt) {
        const int row = wv * 64 + qt * 16 + l16;
        #pragma unroll
        for (int ks = 0; ks < 2; ++ks) {
            const int c = (quad | (ks << 2)) ^ xr;
            bq[qt][ks] = *(const short8*)&qps[row * 64 + c * 8];
        }
    }

    floatx4 Oa[4][4];   // [ct][qt]: D[c][tt]
    #pragma unroll
    for (int ct = 0; ct < 4; ++ct)
        #pragma unroll
        for (int qt = 0; qt < 4; ++qt) Oa[ct][qt] = (floatx4){0.f, 0.f, 0.f, 0.f};
    float l_part[4] = {0.f, 0.f, 0.f, 0.f};   // per-LANE partial sums

    for (int it = 0; it < NT / 64; ++it) {
        __syncthreads();   // cur tile ready; prev tile frag reads done
        if (it + 1 < NT / 64) {
            const int s0n = (it + 1) * 64;
            short* kb = kt[(it + 1) & 1];
            short* vb = vs[(it + 1) & 1];
            #pragma unroll
            for (int q = 0; q < 2; ++q) {
                const int F = (wv * 2 + q) * 64 + lane;
                const int row = F >> 3, cc = (F & 7) ^ (row & 7);
                gload_lds16(kh + (size_t)(s0n + row) * CH + cc * 8, kb + (wv * 2 + q) * 512);
                gload_lds16(vh + (size_t)row * NT + s0n + cc * 8, vb + (wv * 2 + q) * 512);
            }
        }
        const short* kc = kt[it & 1];
        const short* vc = vs[it & 1];

        // ---- S: D[ss][tt]; each K frag feeds 4 tt-tiles ----
        floatx4 sacc[4][4];   // [nt=ss-tile][qt=tt-tile]
        #pragma unroll
        for (int nt = 0; nt < 4; ++nt)
            #pragma unroll
            for (int qt = 0; qt < 4; ++qt) sacc[nt][qt] = (floatx4){0.f, 0.f, 0.f, 0.f};
        #pragma unroll
        for (int ks = 0; ks < 2; ++ks) {
            const int c = (quad | (ks << 2)) ^ xr;
            #pragma unroll
            for (int nt = 0; nt < 4; ++nt) {
                short8 ak = *(const short8*)&kc[(nt * 16 + l16) * 64 + c * 8];
                #pragma unroll
                for (int qt = 0; qt < 4; ++qt)
                    sacc[nt][qt] = __builtin_amdgcn_mfma_f32_16x16x32_bf16(
                        ak, bq[qt][ks], sacc[nt][qt], 0, 0, 0);
            }
        }

        // ---- softmax: exp2 (no max, exp2 domain), tree-sum to per-lane
        //      partials; cross-lane reduction deferred to epilogue ----
        #pragma unroll
        for (int qt = 0; qt < 4; ++qt) {
            float sn[4];
            #pragma unroll
            for (int nt = 0; nt < 4; ++nt) {
                const float p0 = __builtin_amdgcn_exp2f(sacc[nt][qt][0]);
                const float p1 = __builtin_amdgcn_exp2f(sacc[nt][qt][1]);
                const float p2 = __builtin_amdgcn_exp2f(sacc[nt][qt][2]);
                const float p3 = __builtin_amdgcn_exp2f(sacc[nt][qt][3]);
                sacc[nt][qt][0] = p0; sacc[nt][qt][1] = p1;
                sacc[nt][qt][2] = p2; sacc[nt][qt][3] = p3;
                sn[nt] = (p0 + p1) + (p2 + p3);
            }
            l_part[qt] += (sn[0] + sn[1]) + (sn[2] + sn[3]);
        }

        // ---- write P (bf16 trunc, swizzled) into wave-private qps rows ----
        #pragma unroll
        for (int qt = 0; qt < 4; ++qt) {
            const int row = wv * 64 + qt * 16 + l16;
            #pragma unroll
            for (int nt = 0; nt < 4; ++nt) {
                const int cw = (2 * nt + (quad >> 1)) ^ xr;
                int2 pv;
                pv.x = pk2bf_trunc(sacc[nt][qt][0], sacc[nt][qt][1]);
                pv.y = pk2bf_trunc(sacc[nt][qt][2], sacc[nt][qt][3]);
                *(int2*)&qps[row * 64 + cw * 8 + (quad & 1) * 4] = pv;
            }
        }
        // no barrier: rows wave-private; DS pipe in-order per wave

        // ---- PV: D[c][tt]; each V frag feeds 4 tt-tiles ----
        #pragma unroll
        for (int ks = 0; ks < 2; ++ks) {
            const int c = (quad | (ks << 2)) ^ xr;
            short8 bp[4];
            #pragma unroll
            for (int qt = 0; qt < 4; ++qt)
                bp[qt] = *(const short8*)&qps[(wv * 64 + qt * 16 + l16) * 64 + c * 8];
            #pragma unroll
            for (int ct = 0; ct < 4; ++ct) {
                short8 av = *(const short8*)&vc[(ct * 16 + l16) * 64 + c * 8];
                #pragma unroll
                for (int qt = 0; qt < 4; ++qt)
                    Oa[ct][qt] = __builtin_amdgcn_mfma_f32_16x16x32_bf16(
                        av, bp[qt], Oa[ct][qt], 0, 0, 0);
            }
        }
    }

    // epilogue: reduce l across the 4 quads (16-lane groups hold one tt each),
    // normalize, write attn_t[b][t][hd*64+c]
    #pragma unroll
    for (int qt = 0; qt < 4; ++qt) {
        float l = l_part[qt];
        l += __shfl_xor(l, 16, 64);
        l += __shfl_xor(l, 32, 64);
        const float rl = 1.f / l;
        const int t = t0 + wv * 64 + qt * 16 + l16;
        short* dst = at + ((size_t)b * NT + t) * NC + hd * CH;
        #pragma unroll
        for (int ct = 0; ct < 4; ++ct) {
            int2 s;
            s.x = pk2bf_trunc(Oa[ct][qt][0] * rl, Oa[ct][qt][1] * rl);
            s.y = pk2bf_trunc(Oa[ct][qt][2] * rl, Oa[ct][qt][3] * rl);
            *(int2*)&dst[ct * 16 + quad * 4] = s;
        }
    }
}

// ---------------------------------------------------------------------------
// Proj GEMM + bias + residual
// ---------------------------------------------------------------------------
__global__ __launch_bounds__(256) void proj_gemm_kernel(
    const short* __restrict__ wb, const short* __restrict__ at,
    const float* __restrict__ bias, const float* __restrict__ xres,
    float* __restrict__ out)
{
    __shared__ short As[128 * BK];
    __shared__ short Bs[128 * BK];
    const int tid = threadIdx.x;
    const int wv = tid >> 6, lane = tid & 63;
    const int l16 = lane & 15, quad = lane >> 4;
    const int n0 = blockIdx.x * 128;
    const int m0 = blockIdx.y * 128;
    const int wm = wv & 1, wn = wv >> 1;

    floatx4 acc[4][4];
    #pragma unroll
    for (int i = 0; i < 4; ++i)
        #pragma unroll
        for (int j = 0; j < 4; ++j) acc[i][j] = (floatx4){0.f, 0.f, 0.f, 0.f};

    const short* gsrc = (wv < 2) ? wb : at;
    const int rbase = (wv & 1) * 64;
    const int tile0 = (wv < 2) ? m0 : n0;
    short* lbuf = (wv < 2) ? As : Bs;
    const int lrow = lane >> 2;
    const int lcol = (lane & 3) * 8;

    for (int k0 = 0; k0 < 512; k0 += BK) {
        __syncthreads();
        #pragma unroll
        for (int ch = 0; ch < 4; ++ch) {
            const int row = rbase + ch * 16 + lrow;
            gload_lds16(gsrc + (size_t)(tile0 + row) * 512 + k0 + lcol,
                        lbuf + (rbase + ch * 16) * BK);
        }
        __syncthreads();

        short8 af[4], bfr[4];
        #pragma unroll
        for (int i = 0; i < 4; ++i) {
            af[i]  = *(const short8*)&As[(wm * 64 + i * 16 + l16) * BK + quad * 8];
            bfr[i] = *(const short8*)&Bs[(wn * 64 + i * 16 + l16) * BK + quad * 8];
        }
        #pragma unroll
        for (int i = 0; i < 4; ++i)
            #pragma unroll
            for (int j = 0; j < 4; ++j)
                acc[i][j] = __builtin_amdgcn_mfma_f32_16x16x32_bf16(
                    af[i], bfr[j], acc[i][j], 0, 0, 0);
    }

    #pragma unroll
    for (int i = 0; i < 4; ++i) {
        const int o16 = m0 + wm * 64 + i * 16;
        const float4 b4 = *(const float4*)&bias[o16 + quad * 4];
        #pragma unroll
        for (int j = 0; j < 4; ++j) {
            const int tg = n0 + wn * 64 + j * 16 + l16;
            const int b = tg >> 11, t = tg & 2047;
            const size_t base = ((size_t)b * NC + o16 + quad * 4) * NT + t;
            floatx4 v = acc[i][j];
            out[base]          = v[0] + b4.x + xres[base];
            out[base + NT]     = v[1] + b4.y + xres[base + NT];
            out[base + 2 * NT] = v[2] + b4.z + xres[base + 2 * NT];
            out[base + 3 * NT] = v[3] + b4.w + xres[base + 3 * NT];
        }
    }
}

// ---------------------------------------------------------------------------
extern "C" void kernel_launch(void* const* d_in, const int* in_sizes, int n_in,
                              void* d_out, int out_size, void* d_ws, size_t ws_size,
                              hipStream_t stream)
{
    const float* x      = (const float*)d_in[0];
    const float* gn_w   = (const float*)d_in[1];
    const float* gn_b   = (const float*)d_in[2];
    const float* qkv_w  = (const float*)d_in[3];
    const float* qkv_b  = (const float*)d_in[4];
    const float* proj_w = (const float*)d_in[5];
    const float* proj_b = (const float*)d_in[6];
    float* out = (float*)d_out;

    short* ht  = (short*)d_ws;            // [8*2048][512]
    short* q_t = ht  + 8388608;           // [64][2048][64]
    short* k_t = q_t + 8388608;
    short* vv  = k_t + 8388608;           // [64][64][2048]
    short* at  = vv  + 8388608;           // [8*2048][512]
    short* qwb = at  + 8388608;           // [1536][512]
    short* pwb = qwb + 786432;            // [512][512]
    float* stats = (float*)(pwb + 262144);

    castw_kernel<<<768, 256, 0, stream>>>(qkv_w, qwb, 1536 * 512 / 4);
    castw_kernel<<<256, 256, 0, stream>>>(proj_w, pwb, 512 * 512 / 4);
    gn_stats_kernel<<<NB * NG, 256, 0, stream>>>(x, stats);
    gn_apply_kernel<<<dim3(NT / 64, NB), 256, 0, stream>>>(x, gn_w, gn_b, stats, ht);
    qkv_gemm_kernel<<<dim3(128, 12), 256, 0, stream>>>(qwb, ht, qkv_b, q_t, k_t, vv);
    attn_kernel<<<dim3(NT / 256, NB * NH), 256, 0, stream>>>(q_t, k_t, vv, at);
    proj_gemm_kernel<<<dim3(128, 4), 256, 0, stream>>>(pwb, at, proj_b, x, out);
}

// Round 8
// 264.059 us; speedup vs baseline: 6.1606x; 1.0102x over previous
//
#include <hip/hip_runtime.h>
#include <hip/hip_bf16.h>
#include <math.h>

// Problem constants: B=8, C=512, T=2048, G=32, HEADS=8, CH=64
#define NB 8
#define NC 512
#define NT 2048
#define NG 32
#define NH 8
#define CH 64

typedef __attribute__((ext_vector_type(8))) short short8;   // 8 bf16
typedef __attribute__((ext_vector_type(4))) short short4v;  // 4 bf16 (8B)
typedef __attribute__((ext_vector_type(4))) float floatx4;  // MFMA C/D

static __device__ __forceinline__ short f2bf(float f) {
    __hip_bfloat16 h = __float2bfloat16(f);
    return *reinterpret_cast<short*>(&h);
}

// pack high halves of two f32 (truncation to bf16): 1 v_perm_b32
static __device__ __forceinline__ int pk2bf_trunc(float lo, float hi) {
    return (int)__builtin_amdgcn_perm(__builtin_bit_cast(unsigned, hi),
                                      __builtin_bit_cast(unsigned, lo),
                                      0x07060302u);
}

static __device__ __forceinline__ void gload_lds16(const short* g, short* l) {
    __builtin_amdgcn_global_load_lds(
        (const __attribute__((address_space(1))) void*)g,
        (__attribute__((address_space(3))) void*)l, 16, 0, 0);
}

// ---------------------------------------------------------------------------
// fp32 -> bf16 cast of both weight matrices in one launch
// ---------------------------------------------------------------------------
__global__ __launch_bounds__(256) void castw_kernel(
    const float* __restrict__ qw, const float* __restrict__ pw,
    short* __restrict__ qo, short* __restrict__ po)
{
    const int i = blockIdx.x * 256 + threadIdx.x;   // 0..262143 float4 groups
    const bool isq = i < 196608;                    // 1536*512/4
    const int j = isq ? i : i - 196608;
    float4 v = isq ? ((const float4*)qw)[j] : ((const float4*)pw)[j];
    short4v s;
    s.x = f2bf(v.x); s.y = f2bf(v.y); s.z = f2bf(v.z); s.w = f2bf(v.w);
    if (isq) *(short4v*)&qo[j * 4] = s;
    else     *(short4v*)&po[j * 4] = s;
}

// ---------------------------------------------------------------------------
// GroupNorm stats
// ---------------------------------------------------------------------------
__global__ __launch_bounds__(256) void gn_stats_kernel(
    const float* __restrict__ x, float* __restrict__ stats)
{
    __shared__ float red[16];
    const int tid = threadIdx.x;
    const int grp = blockIdx.x;
    const float4* xp = (const float4*)(x + (size_t)grp * 16 * NT);

    float s = 0.f, ss = 0.f;
    for (int i = tid; i < 8192; i += 256) {
        float4 v = xp[i];
        s  += v.x + v.y + v.z + v.w;
        ss += v.x*v.x + v.y*v.y + v.z*v.z + v.w*v.w;
    }
    #pragma unroll
    for (int o = 32; o > 0; o >>= 1) {
        s  += __shfl_down(s,  o, 64);
        ss += __shfl_down(ss, o, 64);
    }
    const int lane = tid & 63, wid = tid >> 6;
    if (lane == 0) { red[wid] = s; red[8 + wid] = ss; }
    __syncthreads();
    if (tid == 0) {
        const float inv = 1.f / 32768.f;
        const float mean = (red[0] + red[1] + red[2] + red[3]) * inv;
        const float var  = (red[8] + red[9] + red[10] + red[11]) * inv - mean * mean;
        stats[grp * 2]     = mean;
        stats[grp * 2 + 1] = rsqrtf(var + 1e-5f);
    }
}

// ---------------------------------------------------------------------------
// GroupNorm apply + transpose + bf16 via LDS tiles (coalesced both sides):
// h_t[b][t][c]. Block = (t-tile 64, b); 8 passes of 64 channels.
// ---------------------------------------------------------------------------
__global__ __launch_bounds__(256) void gn_apply_kernel(
    const float* __restrict__ x, const float* __restrict__ gw,
    const float* __restrict__ gb, const float* __restrict__ stats,
    short* __restrict__ ht)
{
    __shared__ float wc_s[NC], bc_s[NC];
    __shared__ float tile[64 * 68];
    const int tid = threadIdx.x;
    const int b = blockIdx.y;
    const int t0 = blockIdx.x * 64;

    for (int c = tid; c < NC; c += 256) {
        const int g = c >> 4;
        const float mean = stats[(b * NG + g) * 2];
        const float rstd = stats[(b * NG + g) * 2 + 1];
        const float wc = gw[c] * rstd;
        wc_s[c] = wc;
        bc_s[c] = gb[c] - mean * wc;
    }

    const int cl = tid >> 2;            // 0..63 (channel row for load)
    const int k4 = tid & 3;
    const int tl = tid >> 2;            // 0..63 (t row for store)
    const int cs = (tid & 3) * 16;      // c chunk for store

    for (int p = 0; p < 8; ++p) {
        const int c0 = p * 64;
        __syncthreads();   // also covers wc_s init on p==0; tile reuse later
        const float* src = x + ((size_t)b * NC + c0 + cl) * NT + t0;
        #pragma unroll
        for (int k = 0; k < 4; ++k) {
            float4 v = *(const float4*)(src + k4 * 16 + k * 4);
            *(float4*)&tile[cl * 68 + k4 * 16 + k * 4] = v;
        }
        __syncthreads();
        short v16[16];
        #pragma unroll
        for (int j = 0; j < 16; ++j) {
            const int c = c0 + cs + j;
            v16[j] = f2bf(tile[(cs + j) * 68 + tl] * wc_s[c] + bc_s[c]);
        }
        short* dst = ht + ((size_t)b * NT + t0 + tl) * NC + c0 + cs;
        *(short8*)&dst[0] = *(const short8*)&v16[0];
        *(short8*)&dst[8] = *(const short8*)&v16[8];
    }
}

// ---------------------------------------------------------------------------
// QKV GEMM (m97-style). Epilogue: q gets scale*log2e (exp2 softmax),
// k gets scale; v natural layout.
// ---------------------------------------------------------------------------
#define BK 32
__global__ __launch_bounds__(256) void qkv_gemm_kernel(
    const short* __restrict__ wb, const short* __restrict__ ht,
    const float* __restrict__ bias,
    short* __restrict__ q_t, short* __restrict__ k_t, short* __restrict__ vv)
{
    __shared__ short As[128 * BK];
    __shared__ short Bs[128 * BK];
    const int tid = threadIdx.x;
    const int wv = tid >> 6, lane = tid & 63;
    const int l16 = lane & 15, quad = lane >> 4;
    const int n0 = blockIdx.x * 128;
    const int m0 = blockIdx.y * 128;
    const int wm = wv & 1, wn = wv >> 1;

    floatx4 acc[4][4];
    #pragma unroll
    for (int i = 0; i < 4; ++i)
        #pragma unroll
        for (int j = 0; j < 4; ++j) acc[i][j] = (floatx4){0.f, 0.f, 0.f, 0.f};

    const short* gsrc = (wv < 2) ? wb : ht;
    const int rbase = (wv & 1) * 64;
    const int tile0 = (wv < 2) ? m0 : n0;
    short* lbuf = (wv < 2) ? As : Bs;
    const int lrow = lane >> 2;
    const int lcol = (lane & 3) * 8;

    for (int k0 = 0; k0 < 512; k0 += BK) {
        __syncthreads();
        #pragma unroll
        for (int ch = 0; ch < 4; ++ch) {
            const int row = rbase + ch * 16 + lrow;
            gload_lds16(gsrc + (size_t)(tile0 + row) * 512 + k0 + lcol,
                        lbuf + (rbase + ch * 16) * BK);
        }
        __syncthreads();

        short8 af[4], bfr[4];
        #pragma unroll
        for (int i = 0; i < 4; ++i) {
            af[i]  = *(const short8*)&As[(wm * 64 + i * 16 + l16) * BK + quad * 8];
            bfr[i] = *(const short8*)&Bs[(wn * 64 + i * 16 + l16) * BK + quad * 8];
        }
        #pragma unroll
        for (int i = 0; i < 4; ++i)
            #pragma unroll
            for (int j = 0; j < 4; ++j)
                acc[i][j] = __builtin_amdgcn_mfma_f32_16x16x32_bf16(
                    af[i], bfr[j], acc[i][j], 0, 0, 0);
    }

    const float kscale = 0.35355339059327373f;              // 64^-0.25
    const float qscale = 0.35355339059327373f * 1.4426950408889634f; // * log2(e)
    #pragma unroll
    for (int i = 0; i < 4; ++i) {
        const int o16 = m0 + wm * 64 + i * 16;
        const int sel = o16 >> 9;
        const int hh  = (o16 >> 6) & 7;
        const int c16 = o16 & 63;
        const float4 b4 = *(const float4*)&bias[o16 + quad * 4];
        const float sc = (sel == 0) ? qscale : kscale;
        #pragma unroll
        for (int j = 0; j < 4; ++j) {
            const int tg = n0 + wn * 64 + j * 16 + l16;
            const int b = tg >> 11, t = tg & 2047;
            floatx4 v = acc[i][j];
            v[0] += b4.x; v[1] += b4.y; v[2] += b4.z; v[3] += b4.w;
            if (sel < 2) {
                short4v s;
                s.x = f2bf(v[0] * sc); s.y = f2bf(v[1] * sc);
                s.z = f2bf(v[2] * sc); s.w = f2bf(v[3] * sc);
                short* dst = (sel == 0 ? q_t : k_t) +
                    (((size_t)(b * NH + hh) * NT + t) * CH + c16 + quad * 4);
                *(short4v*)dst = s;
            } else {
                short* dst = vv + ((size_t)(b * NH + hh) * CH + c16 + quad * 4) * NT + t;
                #pragma unroll
                for (int r = 0; r < 4; ++r) dst[(size_t)r * NT] = f2bf(v[r]);
            }
        }
    }
}

// ---------------------------------------------------------------------------
// Flash attention v7: occupancy build. Block = 256 tt x 1 bh, **8 waves**
// (512 thr); wave owns 32 tt (2 tiles of 16). Register tile ~110 VGPR
// (bq 16 + Oa 32 + sacc 32) -> under the 128-reg/4-wave step; with 64 KB
// LDS => 2 blocks/CU = 16 waves/CU = 4 waves/SIMD (2x v6). Same XOR-swizzled
// LDS, gload staging, K/V dbuf, no-max exp2 softmax, perm-pack.
// ---------------------------------------------------------------------------
__global__ __launch_bounds__(512, 4) void attn_kernel(
    const short* __restrict__ qg, const short* __restrict__ kg,
    const short* __restrict__ vg, short* __restrict__ at)
{
    __shared__ short qps[256 * 64];      // 32 KB: Q then P (wave-private rows)
    __shared__ short kt[2][64 * 64];     // 16 KB: [ss][c] swizzled, dbuf
    __shared__ short vs[2][64 * 64];     // 16 KB: [c][ss] swizzled, dbuf

    const int tid = threadIdx.x;          // 0..511
    const int wv = tid >> 6, lane = tid & 63;
    const int l16 = lane & 15, quad = lane >> 4;
    const int xr = l16 & 7;
    const int t0 = blockIdx.x * 256;
    const int bh = blockIdx.y;
    const int b = bh >> 3, hd = bh & 7;
    const short* qh = qg + (size_t)bh * NT * CH;
    const short* kh = kg + (size_t)bh * NT * CH;
    const short* vh = vg + (size_t)bh * CH * NT;

    // stage Q: 256 rows; wave wv stages rows [wv*32, +32) (4 gloads)
    #pragma unroll
    for (int q = 0; q < 4; ++q) {
        const int F = (wv * 4 + q) * 64 + lane;
        const int row = F >> 3, cc = (F & 7) ^ (row & 7);
        gload_lds16(qh + (size_t)(t0 + row) * CH + cc * 8, &qps[(wv * 4 + q) * 512]);
    }
    // K/V tile 0 into buf 0: 512 lane-slots each = 1 gload per thread
    {
        const int row = tid >> 3, cc = (tid & 7) ^ (row & 7);
        gload_lds16(kh + (size_t)row * CH + cc * 8, &kt[0][wv * 512]);
        gload_lds16(vh + (size_t)row * NT + cc * 8, &vs[0][wv * 512]);
    }
    __syncthreads();   // Q + tile0 resident

    // hoist Q frags: bq[qt][ks], tt row = wv*32 + qt*16 + l16
    short8 bq[2][2];
    #pragma unroll
    for (int qt = 0; qt < 2; ++qt) {
        const int row = wv * 32 + qt * 16 + l16;
        #pragma unroll
        for (int ks = 0; ks < 2; ++ks) {
            const int c = (quad | (ks << 2)) ^ xr;
            bq[qt][ks] = *(const short8*)&qps[row * 64 + c * 8];
        }
    }

    floatx4 Oa[4][2];   // [ct][qt]: D[c][tt]
    #pragma unroll
    for (int ct = 0; ct < 4; ++ct)
        #pragma unroll
        for (int qt = 0; qt < 2; ++qt) Oa[ct][qt] = (floatx4){0.f, 0.f, 0.f, 0.f};
    float l_part[2] = {0.f, 0.f};   // per-lane partial sums

    for (int it = 0; it < NT / 64; ++it) {
        __syncthreads();   // cur tile ready; prev tile frag reads done
        if (it + 1 < NT / 64) {
            const int s0n = (it + 1) * 64;
            const int row = tid >> 3, cc = (tid & 7) ^ (row & 7);
            gload_lds16(kh + (size_t)(s0n + row) * CH + cc * 8,
                        &kt[(it + 1) & 1][wv * 512]);
            gload_lds16(vh + (size_t)row * NT + s0n + cc * 8,
                        &vs[(it + 1) & 1][wv * 512]);
        }
        const short* kc = kt[it & 1];
        const short* vc = vs[it & 1];

        // ---- S: D[ss][tt]; each K frag feeds 2 tt-tiles ----
        floatx4 sacc[4][2];   // [nt=ss-tile][qt=tt-tile]
        #pragma unroll
        for (int nt = 0; nt < 4; ++nt)
            #pragma unroll
            for (int qt = 0; qt < 2; ++qt) sacc[nt][qt] = (floatx4){0.f, 0.f, 0.f, 0.f};
        #pragma unroll
        for (int ks = 0; ks < 2; ++ks) {
            const int c = (quad | (ks << 2)) ^ xr;
            #pragma unroll
            for (int nt = 0; nt < 4; ++nt) {
                short8 ak = *(const short8*)&kc[(nt * 16 + l16) * 64 + c * 8];
                #pragma unroll
                for (int qt = 0; qt < 2; ++qt)
                    sacc[nt][qt] = __builtin_amdgcn_mfma_f32_16x16x32_bf16(
                        ak, bq[qt][ks], sacc[nt][qt], 0, 0, 0);
            }
        }

        // ---- softmax: exp2 (no max), tree-sum to per-lane partials ----
        #pragma unroll
        for (int qt = 0; qt < 2; ++qt) {
            float sn[4];
            #pragma unroll
            for (int nt = 0; nt < 4; ++nt) {
                const float p0 = __builtin_amdgcn_exp2f(sacc[nt][qt][0]);
                const float p1 = __builtin_amdgcn_exp2f(sacc[nt][qt][1]);
                const float p2 = __builtin_amdgcn_exp2f(sacc[nt][qt][2]);
                const float p3 = __builtin_amdgcn_exp2f(sacc[nt][qt][3]);
                sacc[nt][qt][0] = p0; sacc[nt][qt][1] = p1;
                sacc[nt][qt][2] = p2; sacc[nt][qt][3] = p3;
                sn[nt] = (p0 + p1) + (p2 + p3);
            }
            l_part[qt] += (sn[0] + sn[1]) + (sn[2] + sn[3]);
        }

        // ---- write P (bf16 trunc, swizzled) into wave-private qps rows ----
        #pragma unroll
        for (int qt = 0; qt < 2; ++qt) {
            const int row = wv * 32 + qt * 16 + l16;
            #pragma unroll
            for (int nt = 0; nt < 4; ++nt) {
                const int cw = (2 * nt + (quad >> 1)) ^ xr;
                int2 pv;
                pv.x = pk2bf_trunc(sacc[nt][qt][0], sacc[nt][qt][1]);
                pv.y = pk2bf_trunc(sacc[nt][qt][2], sacc[nt][qt][3]);
                *(int2*)&qps[row * 64 + cw * 8 + (quad & 1) * 4] = pv;
            }
        }
        // no barrier: rows wave-private; DS pipe in-order per wave

        // ---- PV: D[c][tt]; each V frag feeds 2 tt-tiles ----
        #pragma unroll
        for (int ks = 0; ks < 2; ++ks) {
            const int c = (quad | (ks << 2)) ^ xr;
            short8 bp[2];
            #pragma unroll
            for (int qt = 0; qt < 2; ++qt)
                bp[qt] = *(const short8*)&qps[(wv * 32 + qt * 16 + l16) * 64 + c * 8];
            #pragma unroll
            for (int ct = 0; ct < 4; ++ct) {
                short8 av = *(const short8*)&vc[(ct * 16 + l16) * 64 + c * 8];
                #pragma unroll
                for (int qt = 0; qt < 2; ++qt)
                    Oa[ct][qt] = __builtin_amdgcn_mfma_f32_16x16x32_bf16(
                        av, bp[qt], Oa[ct][qt], 0, 0, 0);
            }
        }
    }

    // epilogue: reduce l across quads, normalize, write attn_t[b][t][hd*64+c]
    #pragma unroll
    for (int qt = 0; qt < 2; ++qt) {
        float l = l_part[qt];
        l += __shfl_xor(l, 16, 64);
        l += __shfl_xor(l, 32, 64);
        const float rl = 1.f / l;
        const int t = t0 + wv * 32 + qt * 16 + l16;
        short* dst = at + ((size_t)b * NT + t) * NC + hd * CH;
        #pragma unroll
        for (int ct = 0; ct < 4; ++ct) {
            int2 s;
            s.x = pk2bf_trunc(Oa[ct][qt][0] * rl, Oa[ct][qt][1] * rl);
            s.y = pk2bf_trunc(Oa[ct][qt][2] * rl, Oa[ct][qt][3] * rl);
            *(int2*)&dst[ct * 16 + quad * 4] = s;
        }
    }
}

// ---------------------------------------------------------------------------
// Proj GEMM + bias + residual
// ---------------------------------------------------------------------------
__global__ __launch_bounds__(256) void proj_gemm_kernel(
    const short* __restrict__ wb, const short* __restrict__ at,
    const float* __restrict__ bias, const float* __restrict__ xres,
    float* __restrict__ out)
{
    __shared__ short As[128 * BK];
    __shared__ short Bs[128 * BK];
    const int tid = threadIdx.x;
    const int wv = tid >> 6, lane = tid & 63;
    const int l16 = lane & 15, quad = lane >> 4;
    const int n0 = blockIdx.x * 128;
    const int m0 = blockIdx.y * 128;
    const int wm = wv & 1, wn = wv >> 1;

    floatx4 acc[4][4];
    #pragma unroll
    for (int i = 0; i < 4; ++i)
        #pragma unroll
        for (int j = 0; j < 4; ++j) acc[i][j] = (floatx4){0.f, 0.f, 0.f, 0.f};

    const short* gsrc = (wv < 2) ? wb : at;
    const int rbase = (wv & 1) * 64;
    const int tile0 = (wv < 2) ? m0 : n0;
    short* lbuf = (wv < 2) ? As : Bs;
    const int lrow = lane >> 2;
    const int lcol = (lane & 3) * 8;

    for (int k0 = 0; k0 < 512; k0 += BK) {
        __syncthreads();
        #pragma unroll
        for (int ch = 0; ch < 4; ++ch) {
            const int row = rbase + ch * 16 + lrow;
            gload_lds16(gsrc + (size_t)(tile0 + row) * 512 + k0 + lcol,
                        lbuf + (rbase + ch * 16) * BK);
        }
        __syncthreads();

        short8 af[4], bfr[4];
        #pragma unroll
        for (int i = 0; i < 4; ++i) {
            af[i]  = *(const short8*)&As[(wm * 64 + i * 16 + l16) * BK + quad * 8];
            bfr[i] = *(const short8*)&Bs[(wn * 64 + i * 16 + l16) * BK + quad * 8];
        }
        #pragma unroll
        for (int i = 0; i < 4; ++i)
            #pragma unroll
            for (int j = 0; j < 4; ++j)
                acc[i][j] = __builtin_amdgcn_mfma_f32_16x16x32_bf16(
                    af[i], bfr[j], acc[i][j], 0, 0, 0);
    }

    #pragma unroll
    for (int i = 0; i < 4; ++i) {
        const int o16 = m0 + wm * 64 + i * 16;
        const float4 b4 = *(const float4*)&bias[o16 + quad * 4];
        #pragma unroll
        for (int j = 0; j < 4; ++j) {
            const int tg = n0 + wn * 64 + j * 16 + l16;
            const int b = tg >> 11, t = tg & 2047;
            const size_t base = ((size_t)b * NC + o16 + quad * 4) * NT + t;
            floatx4 v = acc[i][j];
            out[base]          = v[0] + b4.x + xres[base];
            out[base + NT]     = v[1] + b4.y + xres[base + NT];
            out[base + 2 * NT] = v[2] + b4.z + xres[base + 2 * NT];
            out[base + 3 * NT] = v[3] + b4.w + xres[base + 3 * NT];
        }
    }
}

// ---------------------------------------------------------------------------
extern "C" void kernel_launch(void* const* d_in, const int* in_sizes, int n_in,
                              void* d_out, int out_size, void* d_ws, size_t ws_size,
                              hipStream_t stream)
{
    const float* x      = (const float*)d_in[0];
    const float* gn_w   = (const float*)d_in[1];
    const float* gn_b   = (const float*)d_in[2];
    const float* qkv_w  = (const float*)d_in[3];
    const float* qkv_b  = (const float*)d_in[4];
    const float* proj_w = (const float*)d_in[5];
    const float* proj_b = (const float*)d_in[6];
    float* out = (float*)d_out;

    short* ht  = (short*)d_ws;            // [8*2048][512]
    short* q_t = ht  + 8388608;           // [64][2048][64]
    short* k_t = q_t + 8388608;
    short* vv  = k_t + 8388608;           // [64][64][2048]
    short* at  = vv  + 8388608;           // [8*2048][512]
    short* qwb = at  + 8388608;           // [1536][512]
    short* pwb = qwb + 786432;            // [512][512]
    float* stats = (float*)(pwb + 262144);

    castw_kernel<<<1024, 256, 0, stream>>>(qkv_w, proj_w, qwb, pwb);
    gn_stats_kernel<<<NB * NG, 256, 0, stream>>>(x, stats);
    gn_apply_kernel<<<dim3(NT / 64, NB), 256, 0, stream>>>(x, gn_w, gn_b, stats, ht);
    qkv_gemm_kernel<<<dim3(128, 12), 256, 0, stream>>>(qwb, ht, qkv_b, q_t, k_t, vv);
    attn_kernel<<<dim3(NT / 256, NB * NH), 512, 0, stream>>>(q_t, k_t, vv, at);
    proj_gemm_kernel<<<dim3(128, 4), 256, 0, stream>>>(pwb, at, proj_b, x, out);
}